// Round 3
// baseline (2362.094 us; speedup 1.0000x reference)
//
#include <hip/hip_runtime.h>
#include <hip/hip_bf16.h>
#include <math.h>

#define N_NODES 100000
#define N_EDGES 1600000
#define NFEAT 512
#define NHID 128
#define NCLASS 40

// Bucketed edges: 128 dst nodes per bucket. Aggregation accumulates a whole
// bucket in LDS (128 x 128 fp32), so edges only need bucket-level grouping:
// no per-node sort, no node histogram, no 100K-node scans.
#define BSH 7
#define BNODES (1 << BSH)                                  // 128
#define NBUCK ((N_NODES + BNODES - 1) / BNODES)            // 782

// Partition / hist: edges per block
#define PCHUNK 4096
#define PEPT 16
#define PNB ((N_EDGES + PCHUNK - 1) / PCHUNK)              // 391

typedef short bf16x8 __attribute__((ext_vector_type(8)));
typedef float f32x4 __attribute__((ext_vector_type(4)));

static __device__ __forceinline__ unsigned short f32_to_bf16(float f) {
    unsigned int u = __float_as_uint(f);
    unsigned int r = u + 0x7FFFu + ((u >> 16) & 1u);   // RNE
    return (unsigned short)(r >> 16);
}
static __device__ __forceinline__ float bf16_to_f32(unsigned short h) {
    return __uint_as_float(((unsigned int)h) << 16);
}

// ---------------------------------------------------------------------------
// Fused: bucket histogram (blocks [0,PNB)) + W1 transpose->bf16 (rest).
// LDS-staged hist: 4096 edges/block -> <=782 global atomics to padded slots.
// ---------------------------------------------------------------------------
__global__ __launch_bounds__(256) void bucket_hist_transpose_kernel(
    const int* __restrict__ dst, int* __restrict__ histG,
    const float* __restrict__ W1, unsigned short* __restrict__ Wt, int E)
{
    const int blk = blockIdx.x;
    if (blk >= PNB) {
        int tid2 = (blk - PNB) * 256 + threadIdx.x;    // 65536 total
        int n = tid2 >> 9;
        int k = tid2 & 511;
        Wt[tid2] = f32_to_bf16(W1[k * NHID + n]);
        return;
    }
    __shared__ int hl[NBUCK];
    const int t = threadIdx.x;
    for (int j = t; j < NBUCK; j += 256) hl[j] = 0;
    __syncthreads();
    const int c0 = blk * PCHUNK;
    #pragma unroll
    for (int i = 0; i < PEPT; i++) {
        int e = c0 + t + i * 256;
        if (e < E) atomicAdd(&hl[dst[e] >> BSH], 1);
    }
    __syncthreads();
    for (int j = t; j < NBUCK; j += 256) {
        int c = hl[j];
        if (c) atomicAdd(&histG[j * 16], c);   // 64B-padded counters
    }
}

// ---------------------------------------------------------------------------
// Bucket scan: 782 counts -> exclusive offsets bofs[783] + bcursor init.
// ---------------------------------------------------------------------------
__global__ __launch_bounds__(1024) void bucket_scan_kernel(
    const int* __restrict__ histG, int* __restrict__ bofs,
    int* __restrict__ bcursor)
{
    __shared__ int sh[1024];
    const int t = threadIdx.x;
    int v = (t < NBUCK) ? histG[t * 16] : 0;
    sh[t] = v;
    __syncthreads();
    #pragma unroll
    for (int off = 1; off < 1024; off <<= 1) {
        int u = (t >= off) ? sh[t - off] : 0;
        __syncthreads();
        sh[t] += u;
        __syncthreads();
    }
    if (t < NBUCK) {
        int excl = sh[t] - v;
        bofs[t] = excl;
        bcursor[t] = excl;
    }
    if (t == NBUCK - 1) bofs[NBUCK] = sh[t];
}

// ---------------------------------------------------------------------------
// Partition: LDS-staged scatter of edges into bucket-grouped sortedA.
// Pack: x = src | (dst & 127) << 17  (src < 2^17), y = weight bits.
// ---------------------------------------------------------------------------
__global__ __launch_bounds__(256) void partition_kernel(
    const int* __restrict__ src, const int* __restrict__ dst,
    const float* __restrict__ w, int* __restrict__ bcursor,
    int2* __restrict__ sortedA, int E)
{
    __shared__ int hist[NBUCK];
    __shared__ int bbase[NBUCK];
    const int t = threadIdx.x;
    const int c0 = blockIdx.x * PCHUNK;

    for (int j = t; j < NBUCK; j += 256) hist[j] = 0;
    __syncthreads();

    int  myb[PEPT];
    int2 myv[PEPT];
    #pragma unroll
    for (int i = 0; i < PEPT; i++) {
        int e = c0 + t + i * 256;
        if (e < E) {
            int d = dst[e];
            myb[i] = d >> BSH;
            myv[i] = make_int2(src[e] | ((d & (BNODES - 1)) << 17),
                               __float_as_int(w[e]));
            atomicAdd(&hist[myb[i]], 1);
        } else {
            myb[i] = -1;
        }
    }
    __syncthreads();

    for (int j = t; j < NBUCK; j += 256) {
        int c = hist[j];
        bbase[j] = c ? atomicAdd(&bcursor[j], c) : 0;
    }
    __syncthreads();

    #pragma unroll
    for (int i = 0; i < PEPT; i++) {
        if (myb[i] >= 0) {
            int p = atomicAdd(&bbase[myb[i]], 1);
            sortedA[p] = myv[i];
        }
    }
}

// ---------------------------------------------------------------------------
// GEMM1 (bf16 MFMA): h1b[M,128](bf16) = features[M,512](fp32) @ W1
// ---------------------------------------------------------------------------
__global__ __launch_bounds__(256) void gemm1_mfma_kernel(
    const float* __restrict__ A,            // [M,512]
    const unsigned short* __restrict__ Wt,  // [128][512] bf16, Wt[n][k]
    unsigned short* __restrict__ h1b,       // [M,128] bf16
    int M)
{
    __shared__ unsigned short cstage[4][32 * 130];   // per-wave 32x128 (+2 pad)

    const int tid = threadIdx.x;
    const int w = tid >> 6;
    const int lane = tid & 63;
    const int lr = lane & 15;
    const int quad = lane >> 4;
    const int m0 = blockIdx.x * 128 + w * 32;   // this wave's 32 rows

    f32x4 acc[2][8];
    #pragma unroll
    for (int rt = 0; rt < 2; rt++)
        #pragma unroll
        for (int ct = 0; ct < 8; ct++)
            acc[rt][ct] = (f32x4){0.f, 0.f, 0.f, 0.f};

    int r0 = m0 + lr;
    int r1 = m0 + 16 + lr;
    int r0c = r0 < M ? r0 : M - 1;
    int r1c = r1 < M ? r1 : M - 1;
    const float* a0p = A + (size_t)r0c * NFEAT + quad * 8;
    const float* a1p = A + (size_t)r1c * NFEAT + quad * 8;
    const unsigned short* bp = Wt + (size_t)lr * NFEAT + quad * 8;

    #pragma unroll 2
    for (int k0 = 0; k0 < NFEAT; k0 += 32) {
        float4 a0a = *(const float4*)(a0p + k0);
        float4 a0b = *(const float4*)(a0p + k0 + 4);
        float4 a1a = *(const float4*)(a1p + k0);
        float4 a1b = *(const float4*)(a1p + k0 + 4);

        bf16x8 fb[8];
        #pragma unroll
        for (int ct = 0; ct < 8; ct++)
            fb[ct] = *(const bf16x8*)(bp + (size_t)ct * 16 * NFEAT + k0);

        bf16x8 fa0, fa1;
        fa0[0] = (short)f32_to_bf16(a0a.x); fa0[1] = (short)f32_to_bf16(a0a.y);
        fa0[2] = (short)f32_to_bf16(a0a.z); fa0[3] = (short)f32_to_bf16(a0a.w);
        fa0[4] = (short)f32_to_bf16(a0b.x); fa0[5] = (short)f32_to_bf16(a0b.y);
        fa0[6] = (short)f32_to_bf16(a0b.z); fa0[7] = (short)f32_to_bf16(a0b.w);
        fa1[0] = (short)f32_to_bf16(a1a.x); fa1[1] = (short)f32_to_bf16(a1a.y);
        fa1[2] = (short)f32_to_bf16(a1a.z); fa1[3] = (short)f32_to_bf16(a1a.w);
        fa1[4] = (short)f32_to_bf16(a1b.x); fa1[5] = (short)f32_to_bf16(a1b.y);
        fa1[6] = (short)f32_to_bf16(a1b.z); fa1[7] = (short)f32_to_bf16(a1b.w);

        #pragma unroll
        for (int ct = 0; ct < 8; ct++) {
            acc[0][ct] = __builtin_amdgcn_mfma_f32_16x16x32_bf16(fa0, fb[ct], acc[0][ct], 0, 0, 0);
            acc[1][ct] = __builtin_amdgcn_mfma_f32_16x16x32_bf16(fa1, fb[ct], acc[1][ct], 0, 0, 0);
        }
    }

    unsigned short* st = cstage[w];
    #pragma unroll
    for (int rt = 0; rt < 2; rt++)
        #pragma unroll
        for (int ct = 0; ct < 8; ct++)
            #pragma unroll
            for (int i = 0; i < 4; i++) {
                int row = rt * 16 + quad * 4 + i;
                int col = ct * 16 + lr;
                st[row * 130 + col] = f32_to_bf16(acc[rt][ct][i]);
            }

    #pragma unroll
    for (int g = 0; g < 8; g++) {
        int row = g * 4 + (lane >> 4);          // 0..31
        int c8 = lane & 15;                      // 16B chunk index
        const unsigned short* rp = &st[row * 130 + c8 * 8];
        uint4 v = *(const uint4*)rp;
        int gr = m0 + row;
        if (gr < M)
            *(uint4*)&h1b[(size_t)gr * NHID + c8 * 8] = v;
    }
}

// ---------------------------------------------------------------------------
// agg1 + bias + relu + gemm2, one bucket per block.
// LDS: accf[128 nodes][132] fp32 (dims permuted: word w holds dim
// d=2*(w&63)+(w>>6), so each lane's gathered dword (dims 2l,2l+1) lands at
// conflict-free words l and 64+l). wt2 = W2 bf16 in the SAME permuted order.
// ---------------------------------------------------------------------------
__global__ __launch_bounds__(256) void agg1_gemm2_kernel(
    const int2* __restrict__ sortedA, const int* __restrict__ bofs,
    const unsigned short* __restrict__ h1b, const float* __restrict__ b1,
    const float* __restrict__ W2, float* __restrict__ h2, int N)
{
    __shared__ __align__(16) float accf[128 * 132];          // 67,584 B
    __shared__ __align__(16) unsigned short wt2[40 * 132];   // 10,560 B
    __shared__ float b1p[128];

    const int tid = threadIdx.x;
    const int b = blockIdx.x;
    const int node0 = b << BSH;
    const int nn = min(BNODES, N - node0);

    // init: zero acc, stage W2 (bf16, permuted), stage b1 (permuted)
    for (int i = tid; i < 128 * 132; i += 256) accf[i] = 0.f;
    for (int i = tid; i < 40 * 128; i += 256) {
        int c = i >> 7;
        int w = i & 127;
        int d = ((w & 63) << 1) | (w >> 6);
        wt2[c * 132 + w] = f32_to_bf16(W2[d * NCLASS + c]);
    }
    if (tid < 128) {
        int d = ((tid & 63) << 1) | (tid >> 6);
        b1p[tid] = b1[d];
    }
    __syncthreads();

    const int beg = bofs[b];
    const int end = bofs[b + 1];
    const int wv = tid >> 6;
    const int lane = tid & 63;

    for (int base = beg + wv * 64; base < end; base += 256) {
        const int cnt = min(64, end - base);
        int rx = 0, ry = 0;
        if (lane < cnt) { int2 r = sortedA[base + lane]; rx = r.x; ry = r.y; }
        for (int j0 = 0; j0 < cnt; j0 += 8) {
            const int g = min(8, cnt - j0);
            int xs_[8]; float ws_[8];
            #pragma unroll
            for (int q = 0; q < 8; q++) {
                xs_[q] = __shfl(rx, j0 + q, 64);
                ws_[q] = __int_as_float(__shfl(ry, j0 + q, 64));
            }
            unsigned int vv[8];
            #pragma unroll
            for (int q = 0; q < 8; q++) {
                if (q < g) {
                    const unsigned int* rp =
                        (const unsigned int*)(h1b + (size_t)(xs_[q] & 0x1FFFF) * NHID);
                    vv[q] = rp[lane];            // dims 2*lane, 2*lane+1
                }
            }
            #pragma unroll
            for (int q = 0; q < 8; q++) {
                if (q < g) {
                    float* ar = &accf[((xs_[q] >> 17) & 127) * 132];
                    float lo = bf16_to_f32((unsigned short)(vv[q] & 0xFFFF));
                    float hi = bf16_to_f32((unsigned short)(vv[q] >> 16));
                    unsafeAtomicAdd(&ar[lane], ws_[q] * lo);
                    unsafeAtomicAdd(&ar[64 + lane], ws_[q] * hi);
                }
            }
        }
    }
    __syncthreads();

    // bias + relu in place (permuted layout)
    for (int i = tid; i < (nn << 7); i += 256) {
        int r = i >> 7, w = i & 127;
        int idx = r * 132 + w;
        accf[idx] = fmaxf(accf[idx] + b1p[w], 0.f);
    }
    __syncthreads();

    // gemm2 tile: nn x 40; dot over permuted words matches wt2 order.
    float* hp = h2 + (size_t)node0 * NCLASS;
    for (int o = tid; o < nn * NCLASS; o += 256) {
        int r = o / NCLASS;
        int c = o - r * NCLASS;
        const float* ap = &accf[r * 132];
        const unsigned short* wp = &wt2[c * 132];
        float s = 0.f;
        #pragma unroll
        for (int k = 0; k < 128; k += 4) {
            float4 a4 = *(const float4*)(ap + k);
            ushort4 w4 = *(const ushort4*)(wp + k);
            s = fmaf(a4.x, bf16_to_f32(w4.x), s);
            s = fmaf(a4.y, bf16_to_f32(w4.y), s);
            s = fmaf(a4.z, bf16_to_f32(w4.z), s);
            s = fmaf(a4.w, bf16_to_f32(w4.w), s);
        }
        hp[o] = s;
    }
}

// ---------------------------------------------------------------------------
// agg2 + bias + log_softmax, one bucket per block.
// LDS acc2[128][40] fp32; lanes 0..39 gather h2 row + ds_add.
// ---------------------------------------------------------------------------
__global__ __launch_bounds__(256) void agg2_softmax_kernel(
    const int2* __restrict__ sortedA, const int* __restrict__ bofs,
    const float* __restrict__ h2, const float* __restrict__ b2,
    float* __restrict__ out, int N)
{
    __shared__ __align__(16) float acc2[128 * 40];   // 20,480 B

    const int tid = threadIdx.x;
    const int b = blockIdx.x;
    const int node0 = b << BSH;
    const int nn = min(BNODES, N - node0);

    for (int i = tid; i < 128 * 40; i += 256) acc2[i] = 0.f;
    __syncthreads();

    const int beg = bofs[b];
    const int end = bofs[b + 1];
    const int wv = tid >> 6;
    const int lane = tid & 63;

    for (int base = beg + wv * 64; base < end; base += 256) {
        const int cnt = min(64, end - base);
        int rx = 0, ry = 0;
        if (lane < cnt) { int2 r = sortedA[base + lane]; rx = r.x; ry = r.y; }
        for (int j0 = 0; j0 < cnt; j0 += 8) {
            const int g = min(8, cnt - j0);
            int xs_[8]; float ws_[8];
            #pragma unroll
            for (int q = 0; q < 8; q++) {
                xs_[q] = __shfl(rx, j0 + q, 64);
                ws_[q] = __int_as_float(__shfl(ry, j0 + q, 64));
            }
            float vv[8];
            #pragma unroll
            for (int q = 0; q < 8; q++) {
                if (q < g && lane < NCLASS)
                    vv[q] = h2[(size_t)(xs_[q] & 0x1FFFF) * NCLASS + lane];
            }
            #pragma unroll
            for (int q = 0; q < 8; q++) {
                if (q < g && lane < NCLASS)
                    unsafeAtomicAdd(&acc2[((xs_[q] >> 17) & 127) * NCLASS + lane],
                                    ws_[q] * vv[q]);
            }
        }
    }
    __syncthreads();

    // bias + log_softmax per node; 16-lane groups, lanes 0..9 hold 40 vals.
    const int l16 = tid & 15;
    const int grp = tid >> 4;                 // 0..15
    #pragma unroll
    for (int it = 0; it < 8; it++) {
        int ln = grp + (it << 4);             // 0..127
        bool act = (ln < nn) && (l16 < 10);
        float4 a = {0.f, 0.f, 0.f, 0.f};
        float mx = -INFINITY;
        if (act) {
            a = *(const float4*)&acc2[ln * NCLASS + l16 * 4];
            float4 bb = *(const float4*)&b2[l16 * 4];
            a.x += bb.x; a.y += bb.y; a.z += bb.z; a.w += bb.w;
            mx = fmaxf(fmaxf(a.x, a.y), fmaxf(a.z, a.w));
        }
        #pragma unroll
        for (int o = 8; o > 0; o >>= 1) mx = fmaxf(mx, __shfl_xor(mx, o, 16));
        float sm = act ? expf(a.x - mx) + expf(a.y - mx) +
                         expf(a.z - mx) + expf(a.w - mx) : 0.f;
        #pragma unroll
        for (int o = 8; o > 0; o >>= 1) sm += __shfl_xor(sm, o, 16);
        if (act) {
            float l = mx + logf(sm);
            float4 o4 = {a.x - l, a.y - l, a.z - l, a.w - l};
            *(float4*)&out[(size_t)(node0 + ln) * NCLASS + l16 * 4] = o4;
        }
    }
}

extern "C" void kernel_launch(void* const* d_in, const int* in_sizes, int n_in,
                              void* d_out, int out_size, void* d_ws, size_t ws_size,
                              hipStream_t stream) {
    const float* features = (const float*)d_in[0];
    const int* edge_src   = (const int*)d_in[1];
    const int* edge_dst   = (const int*)d_in[2];
    const float* edge_w   = (const float*)d_in[3];
    const float* W1       = (const float*)d_in[4];
    const float* b1       = (const float*)d_in[5];
    const float* W2       = (const float*)d_in[6];
    const float* b2       = (const float*)d_in[7];
    float* out = (float*)d_out;

    // Workspace layout (bytes from base):
    //   h2:      fp32 [N,40]            @ 0          (16,000,000)
    //   h1b:     bf16 [N,128]           @ 51,200,000 (25,600,000)
    //   Wt:      bf16 [128,512]         @ 76,800,000 (131,072)
    //   histG:   int  [NBUCK*16]        @ 76,931,072 (50,048; 64B-padded)
    //   bofs:    int  [NBUCK+1]         @ 77,000,000 (3,132)
    //   bcursor: int  [NBUCK]           @ 77,010,000 (3,128)
    //   sortedA: int2 [E]               @ 90,540,000 (12,800,000)
    char* base = (char*)d_ws;
    float*          h2       = (float*)base;
    unsigned short* h1b      = (unsigned short*)(base + 51200000);
    unsigned short* Wt       = (unsigned short*)(base + 76800000);
    int*            histG    = (int*)(base + 76931072);
    int*            bofs     = (int*)(base + 77000000);
    int*            bcursor  = (int*)(base + 77010000);
    int2*           sortedA  = (int2*)(base + 90540000);

    hipMemsetAsync(histG, 0, NBUCK * 16 * sizeof(int), stream);

    // bucket hist + W1 transpose fused
    bucket_hist_transpose_kernel<<<PNB + (NFEAT * NHID) / 256, 256, 0, stream>>>(
        edge_dst, histG, W1, Wt, N_EDGES);
    bucket_scan_kernel<<<1, 1024, 0, stream>>>(histG, bofs, bcursor);
    partition_kernel<<<PNB, 256, 0, stream>>>(
        edge_src, edge_dst, edge_w, bcursor, sortedA, N_EDGES);

    // Dense layer 1: bf16 MFMA
    gemm1_mfma_kernel<<<(N_NODES + 127) / 128, 256, 0, stream>>>(features, Wt, h1b, N_NODES);

    // Aggregate 1 + bias + relu + dense layer 2 (bucket-LDS accumulate)
    agg1_gemm2_kernel<<<NBUCK, 256, 0, stream>>>(
        sortedA, bofs, h1b, b1, W2, h2, N_NODES);

    // Aggregate 2 + bias + log_softmax (bucket-LDS accumulate)
    agg2_softmax_kernel<<<NBUCK, 256, 0, stream>>>(
        sortedA, bofs, h2, b2, out, N_NODES);
}

// Round 4
// 620.684 us; speedup vs baseline: 3.8056x; 3.8056x over previous
//
#include <hip/hip_runtime.h>
#include <hip/hip_bf16.h>
#include <math.h>

#define N_NODES 100000
#define N_EDGES 1600000
#define NFEAT 512
#define NHID 128
#define NCLASS 40

// Bucketed edges: 128 dst nodes per bucket; aggregation blocks counting-sort
// their bucket's edges in LDS (integer cursors only — NO float atomics, the
// round-3 failure), then accumulate in registers like round 2.
#define BSH 7
#define BNODES (1 << BSH)                                  // 128
#define NBUCK ((N_NODES + BNODES - 1) / BNODES)            // 782

// Partition / hist: edges per block
#define PCHUNK 4096
#define PEPT 16
#define PNB ((N_EDGES + PCHUNK - 1) / PCHUNK)              // 391

// In-LDS edge staging capacity per bucket (mean 2048, sigma ~45; 3072 = +22s;
// guarded by a correct global-scan fallback).
#define CAP 3072
#define KSTG 12   // CAP / 256

typedef short bf16x8 __attribute__((ext_vector_type(8)));
typedef float f32x4 __attribute__((ext_vector_type(4)));

static __device__ __forceinline__ unsigned short f32_to_bf16(float f) {
    unsigned int u = __float_as_uint(f);
    unsigned int r = u + 0x7FFFu + ((u >> 16) & 1u);   // RNE
    return (unsigned short)(r >> 16);
}
static __device__ __forceinline__ float bf16_to_f32(unsigned short h) {
    return __uint_as_float(((unsigned int)h) << 16);
}

// ---------------------------------------------------------------------------
// Fused: bucket histogram (blocks [0,PNB)) + W1 transpose->bf16 (rest).
// ---------------------------------------------------------------------------
__global__ __launch_bounds__(256) void bucket_hist_transpose_kernel(
    const int* __restrict__ dst, int* __restrict__ histG,
    const float* __restrict__ W1, unsigned short* __restrict__ Wt, int E)
{
    const int blk = blockIdx.x;
    if (blk >= PNB) {
        int tid2 = (blk - PNB) * 256 + threadIdx.x;    // 65536 total
        int n = tid2 >> 9;
        int k = tid2 & 511;
        Wt[tid2] = f32_to_bf16(W1[k * NHID + n]);
        return;
    }
    __shared__ int hl[NBUCK];
    const int t = threadIdx.x;
    for (int j = t; j < NBUCK; j += 256) hl[j] = 0;
    __syncthreads();
    const int c0 = blk * PCHUNK;
    #pragma unroll
    for (int i = 0; i < PEPT; i++) {
        int e = c0 + t + i * 256;
        if (e < E) atomicAdd(&hl[dst[e] >> BSH], 1);
    }
    __syncthreads();
    for (int j = t; j < NBUCK; j += 256) {
        int c = hl[j];
        if (c) atomicAdd(&histG[j * 16], c);   // 64B-padded counters
    }
}

// ---------------------------------------------------------------------------
// Bucket scan: 782 counts -> exclusive offsets bofs[783] + bcursor init.
// ---------------------------------------------------------------------------
__global__ __launch_bounds__(1024) void bucket_scan_kernel(
    const int* __restrict__ histG, int* __restrict__ bofs,
    int* __restrict__ bcursor)
{
    __shared__ int sh[1024];
    const int t = threadIdx.x;
    int v = (t < NBUCK) ? histG[t * 16] : 0;
    sh[t] = v;
    __syncthreads();
    #pragma unroll
    for (int off = 1; off < 1024; off <<= 1) {
        int u = (t >= off) ? sh[t - off] : 0;
        __syncthreads();
        sh[t] += u;
        __syncthreads();
    }
    if (t < NBUCK) {
        int excl = sh[t] - v;
        bofs[t] = excl;
        bcursor[t] = excl;
    }
    if (t == NBUCK - 1) bofs[NBUCK] = sh[t];
}

// ---------------------------------------------------------------------------
// Partition: LDS-staged scatter of edges into bucket-grouped sortedA.
// Pack: x = src | (dst & 127) << 17  (src < 2^17), y = weight bits.
// ---------------------------------------------------------------------------
__global__ __launch_bounds__(256) void partition_kernel(
    const int* __restrict__ src, const int* __restrict__ dst,
    const float* __restrict__ w, int* __restrict__ bcursor,
    int2* __restrict__ sortedA, int E)
{
    __shared__ int hist[NBUCK];
    __shared__ int bbase[NBUCK];
    const int t = threadIdx.x;
    const int c0 = blockIdx.x * PCHUNK;

    for (int j = t; j < NBUCK; j += 256) hist[j] = 0;
    __syncthreads();

    int  myb[PEPT];
    int2 myv[PEPT];
    #pragma unroll
    for (int i = 0; i < PEPT; i++) {
        int e = c0 + t + i * 256;
        if (e < E) {
            int d = dst[e];
            myb[i] = d >> BSH;
            myv[i] = make_int2(src[e] | ((d & (BNODES - 1)) << 17),
                               __float_as_int(w[e]));
            atomicAdd(&hist[myb[i]], 1);
        } else {
            myb[i] = -1;
        }
    }
    __syncthreads();

    for (int j = t; j < NBUCK; j += 256) {
        int c = hist[j];
        bbase[j] = c ? atomicAdd(&bcursor[j], c) : 0;
    }
    __syncthreads();

    #pragma unroll
    for (int i = 0; i < PEPT; i++) {
        if (myb[i] >= 0) {
            int p = atomicAdd(&bbase[myb[i]], 1);
            sortedA[p] = myv[i];
        }
    }
}

// ---------------------------------------------------------------------------
// GEMM1 (bf16 MFMA): h1b[M,128](bf16) = features[M,512](fp32) @ W1
// ---------------------------------------------------------------------------
__global__ __launch_bounds__(256) void gemm1_mfma_kernel(
    const float* __restrict__ A,            // [M,512]
    const unsigned short* __restrict__ Wt,  // [128][512] bf16, Wt[n][k]
    unsigned short* __restrict__ h1b,       // [M,128] bf16
    int M)
{
    __shared__ unsigned short cstage[4][32 * 130];   // per-wave 32x128 (+2 pad)

    const int tid = threadIdx.x;
    const int w = tid >> 6;
    const int lane = tid & 63;
    const int lr = lane & 15;
    const int quad = lane >> 4;
    const int m0 = blockIdx.x * 128 + w * 32;   // this wave's 32 rows

    f32x4 acc[2][8];
    #pragma unroll
    for (int rt = 0; rt < 2; rt++)
        #pragma unroll
        for (int ct = 0; ct < 8; ct++)
            acc[rt][ct] = (f32x4){0.f, 0.f, 0.f, 0.f};

    int r0 = m0 + lr;
    int r1 = m0 + 16 + lr;
    int r0c = r0 < M ? r0 : M - 1;
    int r1c = r1 < M ? r1 : M - 1;
    const float* a0p = A + (size_t)r0c * NFEAT + quad * 8;
    const float* a1p = A + (size_t)r1c * NFEAT + quad * 8;
    const unsigned short* bp = Wt + (size_t)lr * NFEAT + quad * 8;

    #pragma unroll 2
    for (int k0 = 0; k0 < NFEAT; k0 += 32) {
        float4 a0a = *(const float4*)(a0p + k0);
        float4 a0b = *(const float4*)(a0p + k0 + 4);
        float4 a1a = *(const float4*)(a1p + k0);
        float4 a1b = *(const float4*)(a1p + k0 + 4);

        bf16x8 fb[8];
        #pragma unroll
        for (int ct = 0; ct < 8; ct++)
            fb[ct] = *(const bf16x8*)(bp + (size_t)ct * 16 * NFEAT + k0);

        bf16x8 fa0, fa1;
        fa0[0] = (short)f32_to_bf16(a0a.x); fa0[1] = (short)f32_to_bf16(a0a.y);
        fa0[2] = (short)f32_to_bf16(a0a.z); fa0[3] = (short)f32_to_bf16(a0a.w);
        fa0[4] = (short)f32_to_bf16(a0b.x); fa0[5] = (short)f32_to_bf16(a0b.y);
        fa0[6] = (short)f32_to_bf16(a0b.z); fa0[7] = (short)f32_to_bf16(a0b.w);
        fa1[0] = (short)f32_to_bf16(a1a.x); fa1[1] = (short)f32_to_bf16(a1a.y);
        fa1[2] = (short)f32_to_bf16(a1a.z); fa1[3] = (short)f32_to_bf16(a1a.w);
        fa1[4] = (short)f32_to_bf16(a1b.x); fa1[5] = (short)f32_to_bf16(a1b.y);
        fa1[6] = (short)f32_to_bf16(a1b.z); fa1[7] = (short)f32_to_bf16(a1b.w);

        #pragma unroll
        for (int ct = 0; ct < 8; ct++) {
            acc[0][ct] = __builtin_amdgcn_mfma_f32_16x16x32_bf16(fa0, fb[ct], acc[0][ct], 0, 0, 0);
            acc[1][ct] = __builtin_amdgcn_mfma_f32_16x16x32_bf16(fa1, fb[ct], acc[1][ct], 0, 0, 0);
        }
    }

    unsigned short* st = cstage[w];
    #pragma unroll
    for (int rt = 0; rt < 2; rt++)
        #pragma unroll
        for (int ct = 0; ct < 8; ct++)
            #pragma unroll
            for (int i = 0; i < 4; i++) {
                int row = rt * 16 + quad * 4 + i;
                int col = ct * 16 + lr;
                st[row * 130 + col] = f32_to_bf16(acc[rt][ct][i]);
            }

    #pragma unroll
    for (int g = 0; g < 8; g++) {
        int row = g * 4 + (lane >> 4);          // 0..31
        int c8 = lane & 15;                      // 16B chunk index
        const unsigned short* rp = &st[row * 130 + c8 * 8];
        uint4 v = *(const uint4*)rp;
        int gr = m0 + row;
        if (gr < M)
            *(uint4*)&h1b[(size_t)gr * NHID + c8 * 8] = v;
    }
}

// ---------------------------------------------------------------------------
// agg1 + bias + relu + gemm2: one block per bucket.
// 1) stage bucket edges to registers (<=12/thread), count per node (LDS int
//    atomics), scan 128 counts, scatter into per-node-sorted LDS ebuf.
// 2) round-2 style accumulation: 8 groups x 32 lanes, one node per group,
//    edge records read via LDS same-address broadcast (no shfl), 8-deep
//    gather MLP, float4 register acc.
// 3) per 8-node iteration: bias+relu -> xs -> gemm2 tile -> h2.
// ---------------------------------------------------------------------------
__global__ __launch_bounds__(256) void agg1_gemm2_kernel(
    const int2* __restrict__ sortedA, const int* __restrict__ bofs,
    const unsigned short* __restrict__ h1b, const float* __restrict__ b1,
    const float* __restrict__ W2, float* __restrict__ h2, int N)
{
    __shared__ __align__(16) int2 ebuf[CAP];                 // 24,576 B
    __shared__ int ncnt[BNODES];
    __shared__ int nofs[BNODES];
    __shared__ int ncur[BNODES];
    __shared__ int sc[BNODES];
    __shared__ __align__(16) float xs[8][132];               // 4,224 B
    __shared__ __align__(16) unsigned short wt2[40 * 132];   // 10,560 B
    __shared__ float b1s[128];

    const int tid = threadIdx.x;
    const int b = blockIdx.x;
    const int node0 = b << BSH;
    const int nn = min(BNODES, N - node0);
    const int beg = bofs[b];
    const int end = bofs[b + 1];
    const int cnt = end - beg;
    const bool fits = (cnt <= CAP);

    // stage W2 (bf16, transposed) + b1
    for (int i = tid; i < 40 * 128; i += 256) {
        int c = i >> 7;
        int k = i & 127;
        wt2[c * 132 + k] = f32_to_bf16(W2[k * NCLASS + c]);
    }
    if (tid < 128) b1s[tid] = b1[tid];
    for (int i = tid; i < BNODES; i += 256) ncnt[i] = 0;
    __syncthreads();

    // ---- in-LDS counting sort of this bucket's edges ----
    int2 myrec[KSTG];
    if (fits) {
        #pragma unroll
        for (int k = 0; k < KSTG; k++) {
            int i = tid + k * 256;
            if (i < cnt) {
                int2 r = sortedA[beg + i];
                myrec[k] = r;
                atomicAdd(&ncnt[(r.x >> 17) & 127], 1);
            }
        }
        __syncthreads();
        // exclusive scan of 128 counts (Hillis-Steele, threads 0..127)
        if (tid < 128) sc[tid] = ncnt[tid];
        __syncthreads();
        #pragma unroll
        for (int off = 1; off < 128; off <<= 1) {
            int u = (tid < 128 && tid >= off) ? sc[tid - off] : 0;
            __syncthreads();
            if (tid < 128) sc[tid] += u;
            __syncthreads();
        }
        if (tid < 128) {
            int e0 = sc[tid] - ncnt[tid];
            nofs[tid] = e0;
            ncur[tid] = e0;
        }
        __syncthreads();
        #pragma unroll
        for (int k = 0; k < KSTG; k++) {
            int i = tid + k * 256;
            if (i < cnt) {
                int nd = (myrec[k].x >> 17) & 127;
                int p = atomicAdd(&ncur[nd], 1);
                ebuf[p] = myrec[k];
            }
        }
        __syncthreads();
    }

    // ---- per-node accumulation + fused gemm2 ----
    const int g = tid >> 5;
    const int lane = tid & 31;
    const unsigned short* hb = h1b + lane * 4;

    for (int it = 0; it < 16; it++) {
        const int ln = it * 8 + g;
        float4 acc = {0.f, 0.f, 0.f, 0.f};
        if (ln < nn) {
            if (fits) {
                const int s0 = nofs[ln];
                const int c0 = ncnt[ln];
                int j = 0;
                for (; j + 8 <= c0; j += 8) {
                    int2 r[8];
                    #pragma unroll
                    for (int q = 0; q < 8; q++) r[q] = ebuf[s0 + j + q];
                    ushort4 hv[8];
                    #pragma unroll
                    for (int q = 0; q < 8; q++)
                        hv[q] = *(const ushort4*)(hb + (size_t)(r[q].x & 0x1FFFF) * NHID);
                    #pragma unroll
                    for (int q = 0; q < 8; q++) {
                        float wj = __int_as_float(r[q].y);
                        acc.x = fmaf(wj, bf16_to_f32(hv[q].x), acc.x);
                        acc.y = fmaf(wj, bf16_to_f32(hv[q].y), acc.y);
                        acc.z = fmaf(wj, bf16_to_f32(hv[q].z), acc.z);
                        acc.w = fmaf(wj, bf16_to_f32(hv[q].w), acc.w);
                    }
                }
                for (; j + 4 <= c0; j += 4) {
                    int2 r[4];
                    #pragma unroll
                    for (int q = 0; q < 4; q++) r[q] = ebuf[s0 + j + q];
                    ushort4 hv[4];
                    #pragma unroll
                    for (int q = 0; q < 4; q++)
                        hv[q] = *(const ushort4*)(hb + (size_t)(r[q].x & 0x1FFFF) * NHID);
                    #pragma unroll
                    for (int q = 0; q < 4; q++) {
                        float wj = __int_as_float(r[q].y);
                        acc.x = fmaf(wj, bf16_to_f32(hv[q].x), acc.x);
                        acc.y = fmaf(wj, bf16_to_f32(hv[q].y), acc.y);
                        acc.z = fmaf(wj, bf16_to_f32(hv[q].z), acc.z);
                        acc.w = fmaf(wj, bf16_to_f32(hv[q].w), acc.w);
                    }
                }
                for (; j < c0; j++) {
                    int2 r = ebuf[s0 + j];
                    float wj = __int_as_float(r.y);
                    ushort4 hv = *(const ushort4*)(hb + (size_t)(r.x & 0x1FFFF) * NHID);
                    acc.x = fmaf(wj, bf16_to_f32(hv.x), acc.x);
                    acc.y = fmaf(wj, bf16_to_f32(hv.y), acc.y);
                    acc.z = fmaf(wj, bf16_to_f32(hv.z), acc.z);
                    acc.w = fmaf(wj, bf16_to_f32(hv.w), acc.w);
                }
            } else {
                // fallback (never for this graph): filter-scan global range
                for (int e = beg; e < end; e++) {
                    int2 r = sortedA[e];
                    if (((r.x >> 17) & 127) == ln) {
                        float wj = __int_as_float(r.y);
                        ushort4 hv = *(const ushort4*)(hb + (size_t)(r.x & 0x1FFFF) * NHID);
                        acc.x = fmaf(wj, bf16_to_f32(hv.x), acc.x);
                        acc.y = fmaf(wj, bf16_to_f32(hv.y), acc.y);
                        acc.z = fmaf(wj, bf16_to_f32(hv.z), acc.z);
                        acc.w = fmaf(wj, bf16_to_f32(hv.w), acc.w);
                    }
                }
            }
            float4 bb = *(const float4*)&b1s[lane * 4];
            acc.x = fmaxf(acc.x + bb.x, 0.f);
            acc.y = fmaxf(acc.y + bb.y, 0.f);
            acc.z = fmaxf(acc.z + bb.z, 0.f);
            acc.w = fmaxf(acc.w + bb.w, 0.f);
            *(float4*)&xs[g][lane * 4] = acc;
        }
        __syncthreads();

        // gemm2 tile for nodes [node0+it*8, +8): 8 x 40 dots of length 128
        float* hp = h2 + (size_t)(node0 + it * 8) * NCLASS;
        #pragma unroll
        for (int i = 0; i < 2; i++) {
            int o = tid + i * 256;
            if (o < 8 * NCLASS) {
                int row = o / NCLASS;
                int col = o - row * NCLASS;
                if (it * 8 + row < nn) {
                    const float* ap = &xs[row][0];
                    const unsigned short* wp = &wt2[col * 132];
                    float s = 0.f;
                    #pragma unroll
                    for (int k = 0; k < 128; k += 4) {
                        float4 a4 = *(const float4*)(ap + k);
                        ushort4 w4 = *(const ushort4*)(wp + k);
                        s = fmaf(a4.x, bf16_to_f32(w4.x), s);
                        s = fmaf(a4.y, bf16_to_f32(w4.y), s);
                        s = fmaf(a4.z, bf16_to_f32(w4.z), s);
                        s = fmaf(a4.w, bf16_to_f32(w4.w), s);
                    }
                    hp[o] = s;
                }
            }
        }
        __syncthreads();
    }
}

// ---------------------------------------------------------------------------
// agg2 + bias + log_softmax: one block per bucket, same in-LDS counting sort,
// 16 groups x 16 lanes, one node per group per iteration (8 iterations).
// ---------------------------------------------------------------------------
__global__ __launch_bounds__(256) void agg2_softmax_kernel(
    const int2* __restrict__ sortedA, const int* __restrict__ bofs,
    const float* __restrict__ h2, const float* __restrict__ b2,
    float* __restrict__ out, int N)
{
    __shared__ __align__(16) int2 ebuf[CAP];     // 24,576 B
    __shared__ int ncnt[BNODES];
    __shared__ int nofs[BNODES];
    __shared__ int ncur[BNODES];
    __shared__ int sc[BNODES];

    const int tid = threadIdx.x;
    const int b = blockIdx.x;
    const int node0 = b << BSH;
    const int nn = min(BNODES, N - node0);
    const int beg = bofs[b];
    const int end = bofs[b + 1];
    const int cnt = end - beg;
    const bool fits = (cnt <= CAP);

    for (int i = tid; i < BNODES; i += 256) ncnt[i] = 0;
    __syncthreads();

    int2 myrec[KSTG];
    if (fits) {
        #pragma unroll
        for (int k = 0; k < KSTG; k++) {
            int i = tid + k * 256;
            if (i < cnt) {
                int2 r = sortedA[beg + i];
                myrec[k] = r;
                atomicAdd(&ncnt[(r.x >> 17) & 127], 1);
            }
        }
        __syncthreads();
        if (tid < 128) sc[tid] = ncnt[tid];
        __syncthreads();
        #pragma unroll
        for (int off = 1; off < 128; off <<= 1) {
            int u = (tid < 128 && tid >= off) ? sc[tid - off] : 0;
            __syncthreads();
            if (tid < 128) sc[tid] += u;
            __syncthreads();
        }
        if (tid < 128) {
            int e0 = sc[tid] - ncnt[tid];
            nofs[tid] = e0;
            ncur[tid] = e0;
        }
        __syncthreads();
        #pragma unroll
        for (int k = 0; k < KSTG; k++) {
            int i = tid + k * 256;
            if (i < cnt) {
                int nd = (myrec[k].x >> 17) & 127;
                int p = atomicAdd(&ncur[nd], 1);
                ebuf[p] = myrec[k];
            }
        }
        __syncthreads();
    }

    const int grp = tid >> 4;     // 0..15
    const int l16 = tid & 15;
    const float* hp0 = h2 + l16 * 4;

    for (int it = 0; it < 8; it++) {
        const int ln = it * 16 + grp;
        float4 acc = {0.f, 0.f, 0.f, 0.f};
        if (ln < nn) {
            if (fits) {
                const int s0 = nofs[ln];
                const int c0 = ncnt[ln];
                int j = 0;
                for (; j + 8 <= c0; j += 8) {
                    int2 r[8];
                    #pragma unroll
                    for (int q = 0; q < 8; q++) r[q] = ebuf[s0 + j + q];
                    if (l16 < 10) {
                        float4 v[8];
                        #pragma unroll
                        for (int q = 0; q < 8; q++)
                            v[q] = *(const float4*)(hp0 + (size_t)(r[q].x & 0x1FFFF) * NCLASS);
                        #pragma unroll
                        for (int q = 0; q < 8; q++) {
                            float wj = __int_as_float(r[q].y);
                            acc.x = fmaf(wj, v[q].x, acc.x);
                            acc.y = fmaf(wj, v[q].y, acc.y);
                            acc.z = fmaf(wj, v[q].z, acc.z);
                            acc.w = fmaf(wj, v[q].w, acc.w);
                        }
                    }
                }
                for (; j + 4 <= c0; j += 4) {
                    int2 r[4];
                    #pragma unroll
                    for (int q = 0; q < 4; q++) r[q] = ebuf[s0 + j + q];
                    if (l16 < 10) {
                        float4 v[4];
                        #pragma unroll
                        for (int q = 0; q < 4; q++)
                            v[q] = *(const float4*)(hp0 + (size_t)(r[q].x & 0x1FFFF) * NCLASS);
                        #pragma unroll
                        for (int q = 0; q < 4; q++) {
                            float wj = __int_as_float(r[q].y);
                            acc.x = fmaf(wj, v[q].x, acc.x);
                            acc.y = fmaf(wj, v[q].y, acc.y);
                            acc.z = fmaf(wj, v[q].z, acc.z);
                            acc.w = fmaf(wj, v[q].w, acc.w);
                        }
                    }
                }
                for (; j < c0; j++) {
                    int2 r = ebuf[s0 + j];
                    if (l16 < 10) {
                        float wj = __int_as_float(r.y);
                        float4 v = *(const float4*)(hp0 + (size_t)(r.x & 0x1FFFF) * NCLASS);
                        acc.x = fmaf(wj, v.x, acc.x);
                        acc.y = fmaf(wj, v.y, acc.y);
                        acc.z = fmaf(wj, v.z, acc.z);
                        acc.w = fmaf(wj, v.w, acc.w);
                    }
                }
            } else {
                for (int e = beg; e < end; e++) {
                    int2 r = sortedA[e];
                    if (((r.x >> 17) & 127) == ln && l16 < 10) {
                        float wj = __int_as_float(r.y);
                        float4 v = *(const float4*)(hp0 + (size_t)(r.x & 0x1FFFF) * NCLASS);
                        acc.x = fmaf(wj, v.x, acc.x);
                        acc.y = fmaf(wj, v.y, acc.y);
                        acc.z = fmaf(wj, v.z, acc.z);
                        acc.w = fmaf(wj, v.w, acc.w);
                    }
                }
            }
        }
        // bias + log_softmax (16-lane groups; lanes 0..9 hold 40 values)
        bool act = (ln < nn) && (l16 < 10);
        float mx = -INFINITY;
        if (act) {
            float4 bb = *(const float4*)&b2[l16 * 4];
            acc.x += bb.x; acc.y += bb.y; acc.z += bb.z; acc.w += bb.w;
            mx = fmaxf(fmaxf(acc.x, acc.y), fmaxf(acc.z, acc.w));
        }
        #pragma unroll
        for (int o = 8; o > 0; o >>= 1) mx = fmaxf(mx, __shfl_xor(mx, o, 16));
        float sm = act ? expf(acc.x - mx) + expf(acc.y - mx) +
                         expf(acc.z - mx) + expf(acc.w - mx) : 0.f;
        #pragma unroll
        for (int o = 8; o > 0; o >>= 1) sm += __shfl_xor(sm, o, 16);
        if (act) {
            float l = mx + logf(sm);
            float4 o4 = {acc.x - l, acc.y - l, acc.z - l, acc.w - l};
            *(float4*)&out[(size_t)(node0 + ln) * NCLASS + l16 * 4] = o4;
        }
    }
}

extern "C" void kernel_launch(void* const* d_in, const int* in_sizes, int n_in,
                              void* d_out, int out_size, void* d_ws, size_t ws_size,
                              hipStream_t stream) {
    const float* features = (const float*)d_in[0];
    const int* edge_src   = (const int*)d_in[1];
    const int* edge_dst   = (const int*)d_in[2];
    const float* edge_w   = (const float*)d_in[3];
    const float* W1       = (const float*)d_in[4];
    const float* b1       = (const float*)d_in[5];
    const float* W2       = (const float*)d_in[6];
    const float* b2       = (const float*)d_in[7];
    float* out = (float*)d_out;

    // Workspace layout (bytes from base):
    //   h2:      fp32 [N,40]            @ 0          (16,000,000)
    //   h1b:     bf16 [N,128]           @ 51,200,000 (25,600,000)
    //   Wt:      bf16 [128,512]         @ 76,800,000 (131,072)
    //   histG:   int  [NBUCK*16]        @ 76,931,072 (50,048; 64B-padded)
    //   bofs:    int  [NBUCK+1]         @ 77,000,000 (3,132)
    //   bcursor: int  [NBUCK]           @ 77,010,000 (3,128)
    //   sortedA: int2 [E]               @ 90,540,000 (12,800,000)
    char* base = (char*)d_ws;
    float*          h2       = (float*)base;
    unsigned short* h1b      = (unsigned short*)(base + 51200000);
    unsigned short* Wt       = (unsigned short*)(base + 76800000);
    int*            histG    = (int*)(base + 76931072);
    int*            bofs     = (int*)(base + 77000000);
    int*            bcursor  = (int*)(base + 77010000);
    int2*           sortedA  = (int2*)(base + 90540000);

    hipMemsetAsync(histG, 0, NBUCK * 16 * sizeof(int), stream);

    // bucket hist + W1 transpose fused
    bucket_hist_transpose_kernel<<<PNB + (NFEAT * NHID) / 256, 256, 0, stream>>>(
        edge_dst, histG, W1, Wt, N_EDGES);
    bucket_scan_kernel<<<1, 1024, 0, stream>>>(histG, bofs, bcursor);
    partition_kernel<<<PNB, 256, 0, stream>>>(
        edge_src, edge_dst, edge_w, bcursor, sortedA, N_EDGES);

    // Dense layer 1: bf16 MFMA
    gemm1_mfma_kernel<<<(N_NODES + 127) / 128, 256, 0, stream>>>(features, Wt, h1b, N_NODES);

    // Aggregate 1 + bias + relu + dense layer 2 (in-LDS counting sort)
    agg1_gemm2_kernel<<<NBUCK, 256, 0, stream>>>(
        sortedA, bofs, h1b, b1, W2, h2, N_NODES);

    // Aggregate 2 + bias + log_softmax (in-LDS counting sort)
    agg2_softmax_kernel<<<NBUCK, 256, 0, stream>>>(
        sortedA, bofs, h2, b2, out, N_NODES);
}

// Round 5
// 544.851 us; speedup vs baseline: 4.3353x; 1.1392x over previous
//
#include <hip/hip_runtime.h>
#include <hip/hip_bf16.h>
#include <math.h>

#define N_NODES 100000
#define N_EDGES 1600000
#define NFEAT 512
#define NHID 128
#define NCLASS 40

// Bucketed edges: 128 dst nodes per bucket; aggregation blocks counting-sort
// their bucket's edges in LDS (integer cursors only — NO float atomics, the
// round-3 failure), then accumulate in registers (round-4 proven loop).
// Round-5: barrier-free accumulate phase + MFMA gemm2 epilogue.
#define BSH 7
#define BNODES (1 << BSH)                                  // 128
#define NBUCK ((N_NODES + BNODES - 1) / BNODES)            // 782

// Partition / hist: edges per block
#define PCHUNK 4096
#define PEPT 16
#define PNB ((N_EDGES + PCHUNK - 1) / PCHUNK)              // 391

// In-LDS edge staging capacity per bucket (mean 2048, sigma ~45; 2560 = +11s;
// guarded by a correct global-scan fallback).
#define CAP 2560
#define KSTG 10   // CAP / 256

typedef short bf16x8 __attribute__((ext_vector_type(8)));
typedef float f32x4 __attribute__((ext_vector_type(4)));

static __device__ __forceinline__ unsigned short f32_to_bf16(float f) {
    unsigned int u = __float_as_uint(f);
    unsigned int r = u + 0x7FFFu + ((u >> 16) & 1u);   // RNE
    return (unsigned short)(r >> 16);
}
static __device__ __forceinline__ float bf16_to_f32(unsigned short h) {
    return __uint_as_float(((unsigned int)h) << 16);
}

// ---------------------------------------------------------------------------
// Fused: bucket histogram (blocks [0,PNB)) + W1 transpose->bf16 + W2
// transpose->bf16 (zero-padded to 48 classes) in the tail blocks.
// ---------------------------------------------------------------------------
__global__ __launch_bounds__(256) void bucket_hist_transpose_kernel(
    const int* __restrict__ dst, int* __restrict__ histG,
    const float* __restrict__ W1, unsigned short* __restrict__ Wt,
    const float* __restrict__ W2, unsigned short* __restrict__ W2t, int E)
{
    const int blk = blockIdx.x;
    if (blk >= PNB + 256) {
        // W2t[c][k] = bf16(W2[k][c]) for c<40 else 0;  48*128 = 6144 elems
        int i = (blk - PNB - 256) * 256 + threadIdx.x;
        if (i < 48 * 128) {
            int c = i >> 7;
            int k = i & 127;
            W2t[i] = (c < NCLASS) ? f32_to_bf16(W2[k * NCLASS + c]) : 0;
        }
        return;
    }
    if (blk >= PNB) {
        int tid2 = (blk - PNB) * 256 + threadIdx.x;    // 65536 total
        int n = tid2 >> 9;
        int k = tid2 & 511;
        Wt[tid2] = f32_to_bf16(W1[k * NHID + n]);
        return;
    }
    __shared__ int hl[NBUCK];
    const int t = threadIdx.x;
    for (int j = t; j < NBUCK; j += 256) hl[j] = 0;
    __syncthreads();
    const int c0 = blk * PCHUNK;
    #pragma unroll
    for (int i = 0; i < PEPT; i++) {
        int e = c0 + t + i * 256;
        if (e < E) atomicAdd(&hl[dst[e] >> BSH], 1);
    }
    __syncthreads();
    for (int j = t; j < NBUCK; j += 256) {
        int c = hl[j];
        if (c) atomicAdd(&histG[j * 16], c);   // 64B-padded counters
    }
}

// ---------------------------------------------------------------------------
// Bucket scan: 782 counts -> exclusive offsets bofs[783] + bcursor init.
// ---------------------------------------------------------------------------
__global__ __launch_bounds__(1024) void bucket_scan_kernel(
    const int* __restrict__ histG, int* __restrict__ bofs,
    int* __restrict__ bcursor)
{
    __shared__ int sh[1024];
    const int t = threadIdx.x;
    int v = (t < NBUCK) ? histG[t * 16] : 0;
    sh[t] = v;
    __syncthreads();
    #pragma unroll
    for (int off = 1; off < 1024; off <<= 1) {
        int u = (t >= off) ? sh[t - off] : 0;
        __syncthreads();
        sh[t] += u;
        __syncthreads();
    }
    if (t < NBUCK) {
        int excl = sh[t] - v;
        bofs[t] = excl;
        bcursor[t] = excl;
    }
    if (t == NBUCK - 1) bofs[NBUCK] = sh[t];
}

// ---------------------------------------------------------------------------
// Partition: LDS-staged scatter of edges into bucket-grouped sortedA.
// Pack: x = src | (dst & 127) << 17  (src < 2^17), y = weight bits.
// ---------------------------------------------------------------------------
__global__ __launch_bounds__(256) void partition_kernel(
    const int* __restrict__ src, const int* __restrict__ dst,
    const float* __restrict__ w, int* __restrict__ bcursor,
    int2* __restrict__ sortedA, int E)
{
    __shared__ int hist[NBUCK];
    __shared__ int bbase[NBUCK];
    const int t = threadIdx.x;
    const int c0 = blockIdx.x * PCHUNK;

    for (int j = t; j < NBUCK; j += 256) hist[j] = 0;
    __syncthreads();

    int  myb[PEPT];
    int2 myv[PEPT];
    #pragma unroll
    for (int i = 0; i < PEPT; i++) {
        int e = c0 + t + i * 256;
        if (e < E) {
            int d = dst[e];
            myb[i] = d >> BSH;
            myv[i] = make_int2(src[e] | ((d & (BNODES - 1)) << 17),
                               __float_as_int(w[e]));
            atomicAdd(&hist[myb[i]], 1);
        } else {
            myb[i] = -1;
        }
    }
    __syncthreads();

    for (int j = t; j < NBUCK; j += 256) {
        int c = hist[j];
        bbase[j] = c ? atomicAdd(&bcursor[j], c) : 0;
    }
    __syncthreads();

    #pragma unroll
    for (int i = 0; i < PEPT; i++) {
        if (myb[i] >= 0) {
            int p = atomicAdd(&bbase[myb[i]], 1);
            sortedA[p] = myv[i];
        }
    }
}

// ---------------------------------------------------------------------------
// GEMM1 (bf16 MFMA): h1b[M,128](bf16) = features[M,512](fp32) @ W1
// ---------------------------------------------------------------------------
__global__ __launch_bounds__(256) void gemm1_mfma_kernel(
    const float* __restrict__ A,            // [M,512]
    const unsigned short* __restrict__ Wt,  // [128][512] bf16, Wt[n][k]
    unsigned short* __restrict__ h1b,       // [M,128] bf16
    int M)
{
    __shared__ unsigned short cstage[4][32 * 130];   // per-wave 32x128 (+2 pad)

    const int tid = threadIdx.x;
    const int w = tid >> 6;
    const int lane = tid & 63;
    const int lr = lane & 15;
    const int quad = lane >> 4;
    const int m0 = blockIdx.x * 128 + w * 32;   // this wave's 32 rows

    f32x4 acc[2][8];
    #pragma unroll
    for (int rt = 0; rt < 2; rt++)
        #pragma unroll
        for (int ct = 0; ct < 8; ct++)
            acc[rt][ct] = (f32x4){0.f, 0.f, 0.f, 0.f};

    int r0 = m0 + lr;
    int r1 = m0 + 16 + lr;
    int r0c = r0 < M ? r0 : M - 1;
    int r1c = r1 < M ? r1 : M - 1;
    const float* a0p = A + (size_t)r0c * NFEAT + quad * 8;
    const float* a1p = A + (size_t)r1c * NFEAT + quad * 8;
    const unsigned short* bp = Wt + (size_t)lr * NFEAT + quad * 8;

    #pragma unroll 2
    for (int k0 = 0; k0 < NFEAT; k0 += 32) {
        float4 a0a = *(const float4*)(a0p + k0);
        float4 a0b = *(const float4*)(a0p + k0 + 4);
        float4 a1a = *(const float4*)(a1p + k0);
        float4 a1b = *(const float4*)(a1p + k0 + 4);

        bf16x8 fb[8];
        #pragma unroll
        for (int ct = 0; ct < 8; ct++)
            fb[ct] = *(const bf16x8*)(bp + (size_t)ct * 16 * NFEAT + k0);

        bf16x8 fa0, fa1;
        fa0[0] = (short)f32_to_bf16(a0a.x); fa0[1] = (short)f32_to_bf16(a0a.y);
        fa0[2] = (short)f32_to_bf16(a0a.z); fa0[3] = (short)f32_to_bf16(a0a.w);
        fa0[4] = (short)f32_to_bf16(a0b.x); fa0[5] = (short)f32_to_bf16(a0b.y);
        fa0[6] = (short)f32_to_bf16(a0b.z); fa0[7] = (short)f32_to_bf16(a0b.w);
        fa1[0] = (short)f32_to_bf16(a1a.x); fa1[1] = (short)f32_to_bf16(a1a.y);
        fa1[2] = (short)f32_to_bf16(a1a.z); fa1[3] = (short)f32_to_bf16(a1a.w);
        fa1[4] = (short)f32_to_bf16(a1b.x); fa1[5] = (short)f32_to_bf16(a1b.y);
        fa1[6] = (short)f32_to_bf16(a1b.z); fa1[7] = (short)f32_to_bf16(a1b.w);

        #pragma unroll
        for (int ct = 0; ct < 8; ct++) {
            acc[0][ct] = __builtin_amdgcn_mfma_f32_16x16x32_bf16(fa0, fb[ct], acc[0][ct], 0, 0, 0);
            acc[1][ct] = __builtin_amdgcn_mfma_f32_16x16x32_bf16(fa1, fb[ct], acc[1][ct], 0, 0, 0);
        }
    }

    unsigned short* st = cstage[w];
    #pragma unroll
    for (int rt = 0; rt < 2; rt++)
        #pragma unroll
        for (int ct = 0; ct < 8; ct++)
            #pragma unroll
            for (int i = 0; i < 4; i++) {
                int row = rt * 16 + quad * 4 + i;
                int col = ct * 16 + lr;
                st[row * 130 + col] = f32_to_bf16(acc[rt][ct][i]);
            }

    #pragma unroll
    for (int g = 0; g < 8; g++) {
        int row = g * 4 + (lane >> 4);          // 0..31
        int c8 = lane & 15;                      // 16B chunk index
        const unsigned short* rp = &st[row * 130 + c8 * 8];
        uint4 v = *(const uint4*)rp;
        int gr = m0 + row;
        if (gr < M)
            *(uint4*)&h1b[(size_t)gr * NHID + c8 * 8] = v;
    }
}

// ---------------------------------------------------------------------------
// agg1 + bias + relu + gemm2: one block per bucket.
// 1) in-LDS counting sort of the bucket's edges (integer atomics only).
// 2) BARRIER-FREE accumulate: 8 groups x 32 lanes; group g owns nodes
//    [16g,16g+16) back-to-back; finished rows -> bf16 -> xs[128][136] LDS.
// 3) ONE barrier, then MFMA gemm2: h2[128x40] = xs @ W2t (gemm1's proven
//    fragment pattern; 24 mfma/wave).
// ---------------------------------------------------------------------------
__global__ __launch_bounds__(256) void agg1_gemm2_kernel(
    const int2* __restrict__ sortedA, const int* __restrict__ bofs,
    const unsigned short* __restrict__ h1b, const float* __restrict__ b1,
    const unsigned short* __restrict__ W2t, float* __restrict__ h2, int N)
{
    __shared__ __align__(16) int2 ebuf[CAP];                  // 20,480 B
    __shared__ __align__(16) unsigned short xs[128][136];     // 34,816 B
    __shared__ __align__(16) unsigned short wt2s[48 * 136];   // 13,056 B
    __shared__ int ncnt[BNODES];
    __shared__ int nofs[BNODES];
    __shared__ int ncur[BNODES];
    __shared__ int sc[BNODES];
    __shared__ float b1s[128];

    const int tid = threadIdx.x;
    const int b = blockIdx.x;
    const int node0 = b << BSH;
    const int nn = min(BNODES, N - node0);
    const int beg = bofs[b];
    const int end = bofs[b + 1];
    const int cnt = end - beg;
    const bool fits = (cnt <= CAP);

    // stage W2t (bf16 [48][128] -> [48][136]) + b1
    for (int i = tid; i < 48 * 128; i += 256)
        wt2s[(i >> 7) * 136 + (i & 127)] = W2t[i];
    if (tid < 128) {
        b1s[tid] = b1[tid];
        ncnt[tid] = 0;
    }
    __syncthreads();

    // ---- in-LDS counting sort of this bucket's edges ----
    int2 myrec[KSTG];
    if (fits) {
        #pragma unroll
        for (int k = 0; k < KSTG; k++) {
            int i = tid + k * 256;
            if (i < cnt) {
                int2 r = sortedA[beg + i];
                myrec[k] = r;
                atomicAdd(&ncnt[(r.x >> 17) & 127], 1);
            }
        }
        __syncthreads();
        if (tid < 128) sc[tid] = ncnt[tid];
        __syncthreads();
        #pragma unroll
        for (int off = 1; off < 128; off <<= 1) {
            int u = (tid < 128 && tid >= off) ? sc[tid - off] : 0;
            __syncthreads();
            if (tid < 128) sc[tid] += u;
            __syncthreads();
        }
        if (tid < 128) {
            int e0 = sc[tid] - ncnt[tid];
            nofs[tid] = e0;
            ncur[tid] = e0;
        }
        __syncthreads();
        #pragma unroll
        for (int k = 0; k < KSTG; k++) {
            int i = tid + k * 256;
            if (i < cnt) {
                int nd = (myrec[k].x >> 17) & 127;
                int p = atomicAdd(&ncur[nd], 1);
                ebuf[p] = myrec[k];
            }
        }
        __syncthreads();
    }

    // ---- barrier-free accumulate: group g owns nodes [16g, 16g+16) ----
    const int g = tid >> 5;
    const int lane = tid & 31;
    const unsigned short* hb = h1b + lane * 4;

    for (int ln = g * 16; ln < g * 16 + 16; ln++) {
        if (ln >= nn) break;
        float4 acc = {0.f, 0.f, 0.f, 0.f};
        if (fits) {
            const int s0 = nofs[ln];
            const int c0 = ncnt[ln];
            int j = 0;
            for (; j + 8 <= c0; j += 8) {
                int2 r[8];
                #pragma unroll
                for (int q = 0; q < 8; q++) r[q] = ebuf[s0 + j + q];
                ushort4 hv[8];
                #pragma unroll
                for (int q = 0; q < 8; q++)
                    hv[q] = *(const ushort4*)(hb + (size_t)(r[q].x & 0x1FFFF) * NHID);
                #pragma unroll
                for (int q = 0; q < 8; q++) {
                    float wj = __int_as_float(r[q].y);
                    acc.x = fmaf(wj, bf16_to_f32(hv[q].x), acc.x);
                    acc.y = fmaf(wj, bf16_to_f32(hv[q].y), acc.y);
                    acc.z = fmaf(wj, bf16_to_f32(hv[q].z), acc.z);
                    acc.w = fmaf(wj, bf16_to_f32(hv[q].w), acc.w);
                }
            }
            for (; j + 4 <= c0; j += 4) {
                int2 r[4];
                #pragma unroll
                for (int q = 0; q < 4; q++) r[q] = ebuf[s0 + j + q];
                ushort4 hv[4];
                #pragma unroll
                for (int q = 0; q < 4; q++)
                    hv[q] = *(const ushort4*)(hb + (size_t)(r[q].x & 0x1FFFF) * NHID);
                #pragma unroll
                for (int q = 0; q < 4; q++) {
                    float wj = __int_as_float(r[q].y);
                    acc.x = fmaf(wj, bf16_to_f32(hv[q].x), acc.x);
                    acc.y = fmaf(wj, bf16_to_f32(hv[q].y), acc.y);
                    acc.z = fmaf(wj, bf16_to_f32(hv[q].z), acc.z);
                    acc.w = fmaf(wj, bf16_to_f32(hv[q].w), acc.w);
                }
            }
            for (; j < c0; j++) {
                int2 r = ebuf[s0 + j];
                float wj = __int_as_float(r.y);
                ushort4 hv = *(const ushort4*)(hb + (size_t)(r.x & 0x1FFFF) * NHID);
                acc.x = fmaf(wj, bf16_to_f32(hv.x), acc.x);
                acc.y = fmaf(wj, bf16_to_f32(hv.y), acc.y);
                acc.z = fmaf(wj, bf16_to_f32(hv.z), acc.z);
                acc.w = fmaf(wj, bf16_to_f32(hv.w), acc.w);
            }
        } else {
            // fallback (never for this graph): filter-scan global range
            for (int e = beg; e < end; e++) {
                int2 r = sortedA[e];
                if (((r.x >> 17) & 127) == ln) {
                    float wj = __int_as_float(r.y);
                    ushort4 hv = *(const ushort4*)(hb + (size_t)(r.x & 0x1FFFF) * NHID);
                    acc.x = fmaf(wj, bf16_to_f32(hv.x), acc.x);
                    acc.y = fmaf(wj, bf16_to_f32(hv.y), acc.y);
                    acc.z = fmaf(wj, bf16_to_f32(hv.z), acc.z);
                    acc.w = fmaf(wj, bf16_to_f32(hv.w), acc.w);
                }
            }
        }
        float4 bb = *(const float4*)&b1s[lane * 4];
        ushort4 px;
        px.x = f32_to_bf16(fmaxf(acc.x + bb.x, 0.f));
        px.y = f32_to_bf16(fmaxf(acc.y + bb.y, 0.f));
        px.z = f32_to_bf16(fmaxf(acc.z + bb.z, 0.f));
        px.w = f32_to_bf16(fmaxf(acc.w + bb.w, 0.f));
        *(ushort4*)&xs[ln][lane * 4] = px;
    }
    __syncthreads();

    // ---- MFMA gemm2: h2[128][40] = xs(bf16) @ W2t(bf16) ----
    const int wv = tid >> 6;            // wave: rows [wv*32, wv*32+32)
    const int l64 = tid & 63;
    const int lr = l64 & 15;
    const int quad = l64 >> 4;

    f32x4 c_[2][3];
    #pragma unroll
    for (int mt = 0; mt < 2; mt++)
        #pragma unroll
        for (int nt = 0; nt < 3; nt++)
            c_[mt][nt] = (f32x4){0.f, 0.f, 0.f, 0.f};

    #pragma unroll
    for (int k0 = 0; k0 < 128; k0 += 32) {
        bf16x8 af[2], bf_[3];
        #pragma unroll
        for (int mt = 0; mt < 2; mt++)
            af[mt] = *(const bf16x8*)&xs[wv * 32 + mt * 16 + lr][k0 + quad * 8];
        #pragma unroll
        for (int nt = 0; nt < 3; nt++)
            bf_[nt] = *(const bf16x8*)&wt2s[(nt * 16 + lr) * 136 + k0 + quad * 8];
        #pragma unroll
        for (int mt = 0; mt < 2; mt++)
            #pragma unroll
            for (int nt = 0; nt < 3; nt++)
                c_[mt][nt] = __builtin_amdgcn_mfma_f32_16x16x32_bf16(
                    af[mt], bf_[nt], c_[mt][nt], 0, 0, 0);
    }

    #pragma unroll
    for (int mt = 0; mt < 2; mt++)
        #pragma unroll
        for (int nt = 0; nt < 3; nt++) {
            int col = nt * 16 + lr;
            if (col < NCLASS) {
                #pragma unroll
                for (int i = 0; i < 4; i++) {
                    int row = wv * 32 + mt * 16 + quad * 4 + i;
                    if (row < nn)
                        h2[(size_t)(node0 + row) * NCLASS + col] = c_[mt][nt][i];
                }
            }
        }
}

// ---------------------------------------------------------------------------
// agg2 + bias + log_softmax: one block per bucket, same in-LDS counting sort,
// 16 groups x 16 lanes, one node per group per iteration (8 iterations).
// ---------------------------------------------------------------------------
__global__ __launch_bounds__(256) void agg2_softmax_kernel(
    const int2* __restrict__ sortedA, const int* __restrict__ bofs,
    const float* __restrict__ h2, const float* __restrict__ b2,
    float* __restrict__ out, int N)
{
    __shared__ __align__(16) int2 ebuf[CAP];     // 20,480 B
    __shared__ int ncnt[BNODES];
    __shared__ int nofs[BNODES];
    __shared__ int ncur[BNODES];
    __shared__ int sc[BNODES];

    const int tid = threadIdx.x;
    const int b = blockIdx.x;
    const int node0 = b << BSH;
    const int nn = min(BNODES, N - node0);
    const int beg = bofs[b];
    const int end = bofs[b + 1];
    const int cnt = end - beg;
    const bool fits = (cnt <= CAP);

    for (int i = tid; i < BNODES; i += 256) ncnt[i] = 0;
    __syncthreads();

    int2 myrec[KSTG];
    if (fits) {
        #pragma unroll
        for (int k = 0; k < KSTG; k++) {
            int i = tid + k * 256;
            if (i < cnt) {
                int2 r = sortedA[beg + i];
                myrec[k] = r;
                atomicAdd(&ncnt[(r.x >> 17) & 127], 1);
            }
        }
        __syncthreads();
        if (tid < 128) sc[tid] = ncnt[tid];
        __syncthreads();
        #pragma unroll
        for (int off = 1; off < 128; off <<= 1) {
            int u = (tid < 128 && tid >= off) ? sc[tid - off] : 0;
            __syncthreads();
            if (tid < 128) sc[tid] += u;
            __syncthreads();
        }
        if (tid < 128) {
            int e0 = sc[tid] - ncnt[tid];
            nofs[tid] = e0;
            ncur[tid] = e0;
        }
        __syncthreads();
        #pragma unroll
        for (int k = 0; k < KSTG; k++) {
            int i = tid + k * 256;
            if (i < cnt) {
                int nd = (myrec[k].x >> 17) & 127;
                int p = atomicAdd(&ncur[nd], 1);
                ebuf[p] = myrec[k];
            }
        }
        __syncthreads();
    }

    const int grp = tid >> 4;     // 0..15
    const int l16 = tid & 15;
    const float* hp0 = h2 + l16 * 4;

    for (int it = 0; it < 8; it++) {
        const int ln = it * 16 + grp;
        float4 acc = {0.f, 0.f, 0.f, 0.f};
        if (ln < nn) {
            if (fits) {
                const int s0 = nofs[ln];
                const int c0 = ncnt[ln];
                int j = 0;
                for (; j + 8 <= c0; j += 8) {
                    int2 r[8];
                    #pragma unroll
                    for (int q = 0; q < 8; q++) r[q] = ebuf[s0 + j + q];
                    if (l16 < 10) {
                        float4 v[8];
                        #pragma unroll
                        for (int q = 0; q < 8; q++)
                            v[q] = *(const float4*)(hp0 + (size_t)(r[q].x & 0x1FFFF) * NCLASS);
                        #pragma unroll
                        for (int q = 0; q < 8; q++) {
                            float wj = __int_as_float(r[q].y);
                            acc.x = fmaf(wj, v[q].x, acc.x);
                            acc.y = fmaf(wj, v[q].y, acc.y);
                            acc.z = fmaf(wj, v[q].z, acc.z);
                            acc.w = fmaf(wj, v[q].w, acc.w);
                        }
                    }
                }
                for (; j + 4 <= c0; j += 4) {
                    int2 r[4];
                    #pragma unroll
                    for (int q = 0; q < 4; q++) r[q] = ebuf[s0 + j + q];
                    if (l16 < 10) {
                        float4 v[4];
                        #pragma unroll
                        for (int q = 0; q < 4; q++)
                            v[q] = *(const float4*)(hp0 + (size_t)(r[q].x & 0x1FFFF) * NCLASS);
                        #pragma unroll
                        for (int q = 0; q < 4; q++) {
                            float wj = __int_as_float(r[q].y);
                            acc.x = fmaf(wj, v[q].x, acc.x);
                            acc.y = fmaf(wj, v[q].y, acc.y);
                            acc.z = fmaf(wj, v[q].z, acc.z);
                            acc.w = fmaf(wj, v[q].w, acc.w);
                        }
                    }
                }
                for (; j < c0; j++) {
                    int2 r = ebuf[s0 + j];
                    if (l16 < 10) {
                        float wj = __int_as_float(r.y);
                        float4 v = *(const float4*)(hp0 + (size_t)(r.x & 0x1FFFF) * NCLASS);
                        acc.x = fmaf(wj, v.x, acc.x);
                        acc.y = fmaf(wj, v.y, acc.y);
                        acc.z = fmaf(wj, v.z, acc.z);
                        acc.w = fmaf(wj, v.w, acc.w);
                    }
                }
            } else {
                for (int e = beg; e < end; e++) {
                    int2 r = sortedA[e];
                    if (((r.x >> 17) & 127) == ln && l16 < 10) {
                        float wj = __int_as_float(r.y);
                        float4 v = *(const float4*)(hp0 + (size_t)(r.x & 0x1FFFF) * NCLASS);
                        acc.x = fmaf(wj, v.x, acc.x);
                        acc.y = fmaf(wj, v.y, acc.y);
                        acc.z = fmaf(wj, v.z, acc.z);
                        acc.w = fmaf(wj, v.w, acc.w);
                    }
                }
            }
        }
        // bias + log_softmax (16-lane groups; lanes 0..9 hold 40 values)
        bool act = (ln < nn) && (l16 < 10);
        float mx = -INFINITY;
        if (act) {
            float4 bb = *(const float4*)&b2[l16 * 4];
            acc.x += bb.x; acc.y += bb.y; acc.z += bb.z; acc.w += bb.w;
            mx = fmaxf(fmaxf(acc.x, acc.y), fmaxf(acc.z, acc.w));
        }
        #pragma unroll
        for (int o = 8; o > 0; o >>= 1) mx = fmaxf(mx, __shfl_xor(mx, o, 16));
        float sm = act ? expf(acc.x - mx) + expf(acc.y - mx) +
                         expf(acc.z - mx) + expf(acc.w - mx) : 0.f;
        #pragma unroll
        for (int o = 8; o > 0; o >>= 1) sm += __shfl_xor(sm, o, 16);
        if (act) {
            float l = mx + logf(sm);
            float4 o4 = {acc.x - l, acc.y - l, acc.z - l, acc.w - l};
            *(float4*)&out[(size_t)(node0 + ln) * NCLASS + l16 * 4] = o4;
        }
    }
}

extern "C" void kernel_launch(void* const* d_in, const int* in_sizes, int n_in,
                              void* d_out, int out_size, void* d_ws, size_t ws_size,
                              hipStream_t stream) {
    const float* features = (const float*)d_in[0];
    const int* edge_src   = (const int*)d_in[1];
    const int* edge_dst   = (const int*)d_in[2];
    const float* edge_w   = (const float*)d_in[3];
    const float* W1       = (const float*)d_in[4];
    const float* b1       = (const float*)d_in[5];
    const float* W2       = (const float*)d_in[6];
    const float* b2       = (const float*)d_in[7];
    float* out = (float*)d_out;

    // Workspace layout (bytes from base):
    //   h2:      fp32 [N,40]            @ 0          (16,000,000)
    //   h1b:     bf16 [N,128]           @ 51,200,000 (25,600,000)
    //   Wt:      bf16 [128,512]         @ 76,800,000 (131,072)
    //   histG:   int  [NBUCK*16]        @ 76,931,072 (50,048; 64B-padded)
    //   bofs:    int  [NBUCK+1]         @ 77,000,000 (3,132)
    //   bcursor: int  [NBUCK]           @ 77,010,000 (3,128)
    //   W2t:     bf16 [48,128]          @ 77,020,000 (12,288)
    //   sortedA: int2 [E]               @ 90,540,000 (12,800,000)
    char* base = (char*)d_ws;
    float*          h2       = (float*)base;
    unsigned short* h1b      = (unsigned short*)(base + 51200000);
    unsigned short* Wt       = (unsigned short*)(base + 76800000);
    int*            histG    = (int*)(base + 76931072);
    int*            bofs     = (int*)(base + 77000000);
    int*            bcursor  = (int*)(base + 77010000);
    unsigned short* W2t      = (unsigned short*)(base + 77020000);
    int2*           sortedA  = (int2*)(base + 90540000);

    hipMemsetAsync(histG, 0, NBUCK * 16 * sizeof(int), stream);

    // bucket hist + W1/W2 transpose fused (W2t: 24 tail blocks)
    bucket_hist_transpose_kernel<<<PNB + 256 + 24, 256, 0, stream>>>(
        edge_dst, histG, W1, Wt, W2, W2t, N_EDGES);
    bucket_scan_kernel<<<1, 1024, 0, stream>>>(histG, bofs, bcursor);
    partition_kernel<<<PNB, 256, 0, stream>>>(
        edge_src, edge_dst, edge_w, bcursor, sortedA, N_EDGES);

    // Dense layer 1: bf16 MFMA
    gemm1_mfma_kernel<<<(N_NODES + 127) / 128, 256, 0, stream>>>(features, Wt, h1b, N_NODES);

    // Aggregate 1 + bias + relu + dense layer 2 (barrier-free + MFMA epilogue)
    agg1_gemm2_kernel<<<NBUCK, 256, 0, stream>>>(
        sortedA, bofs, h1b, b1, W2t, h2, N_NODES);

    // Aggregate 2 + bias + log_softmax (in-LDS counting sort)
    agg2_softmax_kernel<<<NBUCK, 256, 0, stream>>>(
        sortedA, bofs, h2, b2, out, N_NODES);
}

// Round 6
// 533.675 us; speedup vs baseline: 4.4261x; 1.0209x over previous
//
#include <hip/hip_runtime.h>
#include <hip/hip_bf16.h>
#include <math.h>

#define N_NODES 100000
#define N_EDGES 1600000
#define NFEAT 512
#define NHID 128
#define NCLASS 40

// Bucketed edges: 64 dst nodes per bucket (BSH=6). Aggregation blocks
// counting-sort their bucket's edges in LDS (integer atomics only — round-3
// lesson: NO float atomics on the per-edge path), then accumulate in
// registers barrier-free (round-5 proven), MFMA gemm2 epilogue.
#define BSH 6
#define BNODES (1 << BSH)                                  // 64
#define NBUCK ((N_NODES + BNODES - 1) / BNODES)            // 1563

// hist kernel: edges per block
#define PCHUNK 4096
#define PEPT 16
#define PNB ((N_EDGES + PCHUNK - 1) / PCHUNK)              // 391

// fused partition branch: edges per block (re-read staging, no reg cache)
#define PCHUNK2 8192
#define FPNB ((N_EDGES + PCHUNK2 - 1) / PCHUNK2)           // 196
#define GEMM1_NB ((N_NODES + 127) / 128)                   // 782

// In-LDS edge staging capacity per bucket (mean 1024, sigma ~32; 1536=+16s;
// guarded by a correct global-scan fallback).
#define CAP 1536
#define KSTG 6   // CAP / 256

typedef short bf16x8 __attribute__((ext_vector_type(8)));
typedef float f32x4 __attribute__((ext_vector_type(4)));

static __device__ __forceinline__ unsigned short f32_to_bf16(float f) {
    unsigned int u = __float_as_uint(f);
    unsigned int r = u + 0x7FFFu + ((u >> 16) & 1u);   // RNE
    return (unsigned short)(r >> 16);
}
static __device__ __forceinline__ float bf16_to_f32(unsigned short h) {
    return __uint_as_float(((unsigned int)h) << 16);
}

// ---------------------------------------------------------------------------
// Fused: bucket histogram (blocks [0,PNB)) + W1 transpose->bf16 + W2
// transpose->bf16 (zero-padded to 48 classes) in the tail blocks.
// ---------------------------------------------------------------------------
__global__ __launch_bounds__(256) void bucket_hist_transpose_kernel(
    const int* __restrict__ dst, int* __restrict__ histG,
    const float* __restrict__ W1, unsigned short* __restrict__ Wt,
    const float* __restrict__ W2, unsigned short* __restrict__ W2t, int E)
{
    const int blk = blockIdx.x;
    if (blk >= PNB + 256) {
        // W2t[c][k] = bf16(W2[k][c]) for c<40 else 0;  48*128 = 6144 elems
        int i = (blk - PNB - 256) * 256 + threadIdx.x;
        if (i < 48 * 128) {
            int c = i >> 7;
            int k = i & 127;
            W2t[i] = (c < NCLASS) ? f32_to_bf16(W2[k * NCLASS + c]) : 0;
        }
        return;
    }
    if (blk >= PNB) {
        int tid2 = (blk - PNB) * 256 + threadIdx.x;    // 65536 total
        int n = tid2 >> 9;
        int k = tid2 & 511;
        Wt[tid2] = f32_to_bf16(W1[k * NHID + n]);
        return;
    }
    __shared__ int hl[NBUCK];
    const int t = threadIdx.x;
    for (int j = t; j < NBUCK; j += 256) hl[j] = 0;
    __syncthreads();
    const int c0 = blk * PCHUNK;
    #pragma unroll
    for (int i = 0; i < PEPT; i++) {
        int e = c0 + t + i * 256;
        if (e < E) atomicAdd(&hl[dst[e] >> BSH], 1);
    }
    __syncthreads();
    for (int j = t; j < NBUCK; j += 256) {
        int c = hl[j];
        if (c) atomicAdd(&histG[j * 16], c);   // 64B-padded counters
    }
}

// ---------------------------------------------------------------------------
// Bucket scan: 1563 counts (2 per thread) -> exclusive bofs[NBUCK+1] +
// bcursor init.
// ---------------------------------------------------------------------------
__global__ __launch_bounds__(1024) void bucket_scan_kernel(
    const int* __restrict__ histG, int* __restrict__ bofs,
    int* __restrict__ bcursor)
{
    __shared__ int sh[1024];
    const int t = threadIdx.x;
    const int i0 = 2 * t, i1 = 2 * t + 1;
    int v0 = (i0 < NBUCK) ? histG[i0 * 16] : 0;
    int v1 = (i1 < NBUCK) ? histG[i1 * 16] : 0;
    int s = v0 + v1;
    sh[t] = s;
    __syncthreads();
    #pragma unroll
    for (int off = 1; off < 1024; off <<= 1) {
        int u = (t >= off) ? sh[t - off] : 0;
        __syncthreads();
        sh[t] += u;
        __syncthreads();
    }
    int base = sh[t] - s;
    if (i0 < NBUCK) { bofs[i0] = base;      bcursor[i0] = base; }
    if (i1 < NBUCK) { bofs[i1] = base + v0; bcursor[i1] = base + v0; }
    if (t == 1023) bofs[NBUCK] = sh[1023];
}

// ---------------------------------------------------------------------------
// FUSED partition + gemm1 (independent work, one launch → overlap the
// latency-bound scatter with the BW-bound MFMA GEMM).
//   blocks [0, FPNB):        partition (re-read staging, PCHUNK2 edges)
//   blocks [FPNB, +GEMM1_NB): gemm1 (128 rows each)
// Shared-LDS overlay: gemm1 cstage 33,280B vs partition hist+bbase 12,504B.
// Pack: x = src | (dst & 63) << 17  (src < 2^17), y = weight bits.
// ---------------------------------------------------------------------------
__global__ __launch_bounds__(256) void partition_gemm1_kernel(
    const int* __restrict__ src, const int* __restrict__ dstp,
    const float* __restrict__ w, int* __restrict__ bcursor,
    int2* __restrict__ sortedA,
    const float* __restrict__ A, const unsigned short* __restrict__ Wt,
    unsigned short* __restrict__ h1b, int E, int M)
{
    __shared__ __align__(16) char smem[4 * 32 * 130 * 2];   // 33,280 B

    const int tid = threadIdx.x;

    if (blockIdx.x < FPNB) {
        // ---------------- partition branch ----------------
        int* hist  = (int*)smem;            // [NBUCK]
        int* bbase = hist + NBUCK;          // [NBUCK]
        const int c0 = blockIdx.x * PCHUNK2;

        for (int j = tid; j < NBUCK; j += 256) hist[j] = 0;
        __syncthreads();

        #pragma unroll
        for (int i = 0; i < PCHUNK2 / 256; i++) {
            int e = c0 + tid + i * 256;
            if (e < E) atomicAdd(&hist[dstp[e] >> BSH], 1);
        }
        __syncthreads();

        for (int j = tid; j < NBUCK; j += 256) {
            int c = hist[j];
            bbase[j] = c ? atomicAdd(&bcursor[j], c) : 0;
        }
        __syncthreads();

        #pragma unroll
        for (int i = 0; i < PCHUNK2 / 256; i++) {
            int e = c0 + tid + i * 256;
            if (e < E) {
                int d = dstp[e];                      // L2-hot re-read
                int p = atomicAdd(&bbase[d >> BSH], 1);
                sortedA[p] = make_int2(src[e] | ((d & (BNODES - 1)) << 17),
                                       __float_as_int(w[e]));
            }
        }
        return;
    }

    // ---------------- gemm1 branch ----------------
    unsigned short (*cstage)[32 * 130] = (unsigned short (*)[32 * 130])smem;

    const int w4 = tid >> 6;
    const int lane = tid & 63;
    const int lr = lane & 15;
    const int quad = lane >> 4;
    const int m0 = (blockIdx.x - FPNB) * 128 + w4 * 32;

    f32x4 acc[2][8];
    #pragma unroll
    for (int rt = 0; rt < 2; rt++)
        #pragma unroll
        for (int ct = 0; ct < 8; ct++)
            acc[rt][ct] = (f32x4){0.f, 0.f, 0.f, 0.f};

    int r0 = m0 + lr;
    int r1 = m0 + 16 + lr;
    int r0c = r0 < M ? r0 : M - 1;
    int r1c = r1 < M ? r1 : M - 1;
    const float* a0p = A + (size_t)r0c * NFEAT + quad * 8;
    const float* a1p = A + (size_t)r1c * NFEAT + quad * 8;
    const unsigned short* bp = Wt + (size_t)lr * NFEAT + quad * 8;

    #pragma unroll 2
    for (int k0 = 0; k0 < NFEAT; k0 += 32) {
        float4 a0a = *(const float4*)(a0p + k0);
        float4 a0b = *(const float4*)(a0p + k0 + 4);
        float4 a1a = *(const float4*)(a1p + k0);
        float4 a1b = *(const float4*)(a1p + k0 + 4);

        bf16x8 fb[8];
        #pragma unroll
        for (int ct = 0; ct < 8; ct++)
            fb[ct] = *(const bf16x8*)(bp + (size_t)ct * 16 * NFEAT + k0);

        bf16x8 fa0, fa1;
        fa0[0] = (short)f32_to_bf16(a0a.x); fa0[1] = (short)f32_to_bf16(a0a.y);
        fa0[2] = (short)f32_to_bf16(a0a.z); fa0[3] = (short)f32_to_bf16(a0a.w);
        fa0[4] = (short)f32_to_bf16(a0b.x); fa0[5] = (short)f32_to_bf16(a0b.y);
        fa0[6] = (short)f32_to_bf16(a0b.z); fa0[7] = (short)f32_to_bf16(a0b.w);
        fa1[0] = (short)f32_to_bf16(a1a.x); fa1[1] = (short)f32_to_bf16(a1a.y);
        fa1[2] = (short)f32_to_bf16(a1a.z); fa1[3] = (short)f32_to_bf16(a1a.w);
        fa1[4] = (short)f32_to_bf16(a1b.x); fa1[5] = (short)f32_to_bf16(a1b.y);
        fa1[6] = (short)f32_to_bf16(a1b.z); fa1[7] = (short)f32_to_bf16(a1b.w);

        #pragma unroll
        for (int ct = 0; ct < 8; ct++) {
            acc[0][ct] = __builtin_amdgcn_mfma_f32_16x16x32_bf16(fa0, fb[ct], acc[0][ct], 0, 0, 0);
            acc[1][ct] = __builtin_amdgcn_mfma_f32_16x16x32_bf16(fa1, fb[ct], acc[1][ct], 0, 0, 0);
        }
    }

    unsigned short* st = cstage[w4];
    #pragma unroll
    for (int rt = 0; rt < 2; rt++)
        #pragma unroll
        for (int ct = 0; ct < 8; ct++)
            #pragma unroll
            for (int i = 0; i < 4; i++) {
                int row = rt * 16 + quad * 4 + i;
                int col = ct * 16 + lr;
                st[row * 130 + col] = f32_to_bf16(acc[rt][ct][i]);
            }

    #pragma unroll
    for (int g = 0; g < 8; g++) {
        int row = g * 4 + (lane >> 4);          // 0..31
        int c8 = lane & 15;                      // 16B chunk index
        const unsigned short* rp = &st[row * 130 + c8 * 8];
        uint4 v = *(const uint4*)rp;
        int gr = m0 + row;
        if (gr < M)
            *(uint4*)&h1b[(size_t)gr * NHID + c8 * 8] = v;
    }
}

// ---------------------------------------------------------------------------
// agg1 + bias + relu + gemm2: one block per 64-node bucket.
// 1) in-LDS counting sort (integer atomics only).
// 2) barrier-free accumulate: 8 groups x 32 lanes; group g owns nodes
//    [8g,8g+8) back-to-back; rows -> bf16 -> xs[64][136].
// 3) one barrier, MFMA gemm2: h2[64x40] = xs @ W2t (12 mfma/wave).
// ---------------------------------------------------------------------------
__global__ __launch_bounds__(256) void agg1_gemm2_kernel(
    const int2* __restrict__ sortedA, const int* __restrict__ bofs,
    const unsigned short* __restrict__ h1b, const float* __restrict__ b1,
    const unsigned short* __restrict__ W2t, float* __restrict__ h2, int N)
{
    __shared__ __align__(16) int2 ebuf[CAP];                  // 12,288 B
    __shared__ __align__(16) unsigned short xs[64][136];      // 17,408 B
    __shared__ __align__(16) unsigned short wt2s[48 * 136];   // 13,056 B
    __shared__ int ncnt[BNODES];
    __shared__ int nofs[BNODES];
    __shared__ int ncur[BNODES];
    __shared__ int sc[BNODES];
    __shared__ float b1s[128];

    const int tid = threadIdx.x;
    const int b = blockIdx.x;
    const int node0 = b << BSH;
    const int nn = min(BNODES, N - node0);
    const int beg = bofs[b];
    const int end = bofs[b + 1];
    const int cnt = end - beg;
    const bool fits = (cnt <= CAP);

    // stage W2t (bf16 [48][128] -> [48][136]) + b1
    for (int i = tid; i < 48 * 128; i += 256)
        wt2s[(i >> 7) * 136 + (i & 127)] = W2t[i];
    if (tid < 128) b1s[tid] = b1[tid];
    if (tid < BNODES) ncnt[tid] = 0;
    __syncthreads();

    // ---- in-LDS counting sort of this bucket's edges ----
    int2 myrec[KSTG];
    if (fits) {
        #pragma unroll
        for (int k = 0; k < KSTG; k++) {
            int i = tid + k * 256;
            if (i < cnt) {
                int2 r = sortedA[beg + i];
                myrec[k] = r;
                atomicAdd(&ncnt[(r.x >> 17) & (BNODES - 1)], 1);
            }
        }
        __syncthreads();
        if (tid < BNODES) sc[tid] = ncnt[tid];
        __syncthreads();
        #pragma unroll
        for (int off = 1; off < BNODES; off <<= 1) {
            int u = (tid < BNODES && tid >= off) ? sc[tid - off] : 0;
            __syncthreads();
            if (tid < BNODES) sc[tid] += u;
            __syncthreads();
        }
        if (tid < BNODES) {
            int e0 = sc[tid] - ncnt[tid];
            nofs[tid] = e0;
            ncur[tid] = e0;
        }
        __syncthreads();
        #pragma unroll
        for (int k = 0; k < KSTG; k++) {
            int i = tid + k * 256;
            if (i < cnt) {
                int nd = (myrec[k].x >> 17) & (BNODES - 1);
                int p = atomicAdd(&ncur[nd], 1);
                ebuf[p] = myrec[k];
            }
        }
        __syncthreads();
    }

    // ---- barrier-free accumulate: group g owns nodes [8g, 8g+8) ----
    const int g = tid >> 5;
    const int lane = tid & 31;
    const unsigned short* hb = h1b + lane * 4;

    for (int ln = g * 8; ln < g * 8 + 8; ln++) {
        if (ln >= nn) break;
        float4 acc = {0.f, 0.f, 0.f, 0.f};
        if (fits) {
            const int s0 = nofs[ln];
            const int c0 = ncnt[ln];
            int j = 0;
            for (; j + 8 <= c0; j += 8) {
                int2 r[8];
                #pragma unroll
                for (int q = 0; q < 8; q++) r[q] = ebuf[s0 + j + q];
                ushort4 hv[8];
                #pragma unroll
                for (int q = 0; q < 8; q++)
                    hv[q] = *(const ushort4*)(hb + (size_t)(r[q].x & 0x1FFFF) * NHID);
                #pragma unroll
                for (int q = 0; q < 8; q++) {
                    float wj = __int_as_float(r[q].y);
                    acc.x = fmaf(wj, bf16_to_f32(hv[q].x), acc.x);
                    acc.y = fmaf(wj, bf16_to_f32(hv[q].y), acc.y);
                    acc.z = fmaf(wj, bf16_to_f32(hv[q].z), acc.z);
                    acc.w = fmaf(wj, bf16_to_f32(hv[q].w), acc.w);
                }
            }
            for (; j + 4 <= c0; j += 4) {
                int2 r[4];
                #pragma unroll
                for (int q = 0; q < 4; q++) r[q] = ebuf[s0 + j + q];
                ushort4 hv[4];
                #pragma unroll
                for (int q = 0; q < 4; q++)
                    hv[q] = *(const ushort4*)(hb + (size_t)(r[q].x & 0x1FFFF) * NHID);
                #pragma unroll
                for (int q = 0; q < 4; q++) {
                    float wj = __int_as_float(r[q].y);
                    acc.x = fmaf(wj, bf16_to_f32(hv[q].x), acc.x);
                    acc.y = fmaf(wj, bf16_to_f32(hv[q].y), acc.y);
                    acc.z = fmaf(wj, bf16_to_f32(hv[q].z), acc.z);
                    acc.w = fmaf(wj, bf16_to_f32(hv[q].w), acc.w);
                }
            }
            for (; j < c0; j++) {
                int2 r = ebuf[s0 + j];
                float wj = __int_as_float(r.y);
                ushort4 hv = *(const ushort4*)(hb + (size_t)(r.x & 0x1FFFF) * NHID);
                acc.x = fmaf(wj, bf16_to_f32(hv.x), acc.x);
                acc.y = fmaf(wj, bf16_to_f32(hv.y), acc.y);
                acc.z = fmaf(wj, bf16_to_f32(hv.z), acc.z);
                acc.w = fmaf(wj, bf16_to_f32(hv.w), acc.w);
            }
        } else {
            // fallback (never for this graph): filter-scan global range
            for (int e = beg; e < end; e++) {
                int2 r = sortedA[e];
                if (((r.x >> 17) & (BNODES - 1)) == ln) {
                    float wj = __int_as_float(r.y);
                    ushort4 hv = *(const ushort4*)(hb + (size_t)(r.x & 0x1FFFF) * NHID);
                    acc.x = fmaf(wj, bf16_to_f32(hv.x), acc.x);
                    acc.y = fmaf(wj, bf16_to_f32(hv.y), acc.y);
                    acc.z = fmaf(wj, bf16_to_f32(hv.z), acc.z);
                    acc.w = fmaf(wj, bf16_to_f32(hv.w), acc.w);
                }
            }
        }
        float4 bb = *(const float4*)&b1s[lane * 4];
        ushort4 px;
        px.x = f32_to_bf16(fmaxf(acc.x + bb.x, 0.f));
        px.y = f32_to_bf16(fmaxf(acc.y + bb.y, 0.f));
        px.z = f32_to_bf16(fmaxf(acc.z + bb.z, 0.f));
        px.w = f32_to_bf16(fmaxf(acc.w + bb.w, 0.f));
        *(ushort4*)&xs[ln][lane * 4] = px;
    }
    __syncthreads();

    // ---- MFMA gemm2: h2[64][40] = xs(bf16) @ W2t(bf16) ----
    const int wv = tid >> 6;            // wave: rows [wv*16, wv*16+16)
    const int l64 = tid & 63;
    const int lr = l64 & 15;
    const int quad = l64 >> 4;

    f32x4 c_[3];
    #pragma unroll
    for (int nt = 0; nt < 3; nt++)
        c_[nt] = (f32x4){0.f, 0.f, 0.f, 0.f};

    #pragma unroll
    for (int k0 = 0; k0 < 128; k0 += 32) {
        bf16x8 af = *(const bf16x8*)&xs[wv * 16 + lr][k0 + quad * 8];
        bf16x8 bf_[3];
        #pragma unroll
        for (int nt = 0; nt < 3; nt++)
            bf_[nt] = *(const bf16x8*)&wt2s[(nt * 16 + lr) * 136 + k0 + quad * 8];
        #pragma unroll
        for (int nt = 0; nt < 3; nt++)
            c_[nt] = __builtin_amdgcn_mfma_f32_16x16x32_bf16(
                af, bf_[nt], c_[nt], 0, 0, 0);
    }

    #pragma unroll
    for (int nt = 0; nt < 3; nt++) {
        int col = nt * 16 + lr;
        if (col < NCLASS) {
            #pragma unroll
            for (int i = 0; i < 4; i++) {
                int row = wv * 16 + quad * 4 + i;
                if (row < nn)
                    h2[(size_t)(node0 + row) * NCLASS + col] = c_[nt][i];
            }
        }
    }
}

// ---------------------------------------------------------------------------
// agg2 + bias + log_softmax: one block per 64-node bucket; in-LDS counting
// sort; 16 groups x 16 lanes, 4 iterations of 16 nodes.
// ---------------------------------------------------------------------------
__global__ __launch_bounds__(256) void agg2_softmax_kernel(
    const int2* __restrict__ sortedA, const int* __restrict__ bofs,
    const float* __restrict__ h2, const float* __restrict__ b2,
    float* __restrict__ out, int N)
{
    __shared__ __align__(16) int2 ebuf[CAP];     // 12,288 B
    __shared__ int ncnt[BNODES];
    __shared__ int nofs[BNODES];
    __shared__ int ncur[BNODES];
    __shared__ int sc[BNODES];

    const int tid = threadIdx.x;
    const int b = blockIdx.x;
    const int node0 = b << BSH;
    const int nn = min(BNODES, N - node0);
    const int beg = bofs[b];
    const int end = bofs[b + 1];
    const int cnt = end - beg;
    const bool fits = (cnt <= CAP);

    if (tid < BNODES) ncnt[tid] = 0;
    __syncthreads();

    int2 myrec[KSTG];
    if (fits) {
        #pragma unroll
        for (int k = 0; k < KSTG; k++) {
            int i = tid + k * 256;
            if (i < cnt) {
                int2 r = sortedA[beg + i];
                myrec[k] = r;
                atomicAdd(&ncnt[(r.x >> 17) & (BNODES - 1)], 1);
            }
        }
        __syncthreads();
        if (tid < BNODES) sc[tid] = ncnt[tid];
        __syncthreads();
        #pragma unroll
        for (int off = 1; off < BNODES; off <<= 1) {
            int u = (tid < BNODES && tid >= off) ? sc[tid - off] : 0;
            __syncthreads();
            if (tid < BNODES) sc[tid] += u;
            __syncthreads();
        }
        if (tid < BNODES) {
            int e0 = sc[tid] - ncnt[tid];
            nofs[tid] = e0;
            ncur[tid] = e0;
        }
        __syncthreads();
        #pragma unroll
        for (int k = 0; k < KSTG; k++) {
            int i = tid + k * 256;
            if (i < cnt) {
                int nd = (myrec[k].x >> 17) & (BNODES - 1);
                int p = atomicAdd(&ncur[nd], 1);
                ebuf[p] = myrec[k];
            }
        }
        __syncthreads();
    }

    const int grp = tid >> 4;     // 0..15
    const int l16 = tid & 15;
    const float* hp0 = h2 + l16 * 4;

    for (int it = 0; it < 4; it++) {
        const int ln = it * 16 + grp;
        float4 acc = {0.f, 0.f, 0.f, 0.f};
        if (ln < nn) {
            if (fits) {
                const int s0 = nofs[ln];
                const int c0 = ncnt[ln];
                int j = 0;
                for (; j + 8 <= c0; j += 8) {
                    int2 r[8];
                    #pragma unroll
                    for (int q = 0; q < 8; q++) r[q] = ebuf[s0 + j + q];
                    if (l16 < 10) {
                        float4 v[8];
                        #pragma unroll
                        for (int q = 0; q < 8; q++)
                            v[q] = *(const float4*)(hp0 + (size_t)(r[q].x & 0x1FFFF) * NCLASS);
                        #pragma unroll
                        for (int q = 0; q < 8; q++) {
                            float wj = __int_as_float(r[q].y);
                            acc.x = fmaf(wj, v[q].x, acc.x);
                            acc.y = fmaf(wj, v[q].y, acc.y);
                            acc.z = fmaf(wj, v[q].z, acc.z);
                            acc.w = fmaf(wj, v[q].w, acc.w);
                        }
                    }
                }
                for (; j + 4 <= c0; j += 4) {
                    int2 r[4];
                    #pragma unroll
                    for (int q = 0; q < 4; q++) r[q] = ebuf[s0 + j + q];
                    if (l16 < 10) {
                        float4 v[4];
                        #pragma unroll
                        for (int q = 0; q < 4; q++)
                            v[q] = *(const float4*)(hp0 + (size_t)(r[q].x & 0x1FFFF) * NCLASS);
                        #pragma unroll
                        for (int q = 0; q < 4; q++) {
                            float wj = __int_as_float(r[q].y);
                            acc.x = fmaf(wj, v[q].x, acc.x);
                            acc.y = fmaf(wj, v[q].y, acc.y);
                            acc.z = fmaf(wj, v[q].z, acc.z);
                            acc.w = fmaf(wj, v[q].w, acc.w);
                        }
                    }
                }
                for (; j < c0; j++) {
                    int2 r = ebuf[s0 + j];
                    if (l16 < 10) {
                        float wj = __int_as_float(r.y);
                        float4 v = *(const float4*)(hp0 + (size_t)(r.x & 0x1FFFF) * NCLASS);
                        acc.x = fmaf(wj, v.x, acc.x);
                        acc.y = fmaf(wj, v.y, acc.y);
                        acc.z = fmaf(wj, v.z, acc.z);
                        acc.w = fmaf(wj, v.w, acc.w);
                    }
                }
            } else {
                for (int e = beg; e < end; e++) {
                    int2 r = sortedA[e];
                    if (((r.x >> 17) & (BNODES - 1)) == ln && l16 < 10) {
                        float wj = __int_as_float(r.y);
                        float4 v = *(const float4*)(hp0 + (size_t)(r.x & 0x1FFFF) * NCLASS);
                        acc.x = fmaf(wj, v.x, acc.x);
                        acc.y = fmaf(wj, v.y, acc.y);
                        acc.z = fmaf(wj, v.z, acc.z);
                        acc.w = fmaf(wj, v.w, acc.w);
                    }
                }
            }
        }
        // bias + log_softmax (16-lane groups; lanes 0..9 hold 40 values)
        bool act = (ln < nn) && (l16 < 10);
        float mx = -INFINITY;
        if (act) {
            float4 bb = *(const float4*)&b2[l16 * 4];
            acc.x += bb.x; acc.y += bb.y; acc.z += bb.z; acc.w += bb.w;
            mx = fmaxf(fmaxf(acc.x, acc.y), fmaxf(acc.z, acc.w));
        }
        #pragma unroll
        for (int o = 8; o > 0; o >>= 1) mx = fmaxf(mx, __shfl_xor(mx, o, 16));
        float sm = act ? expf(acc.x - mx) + expf(acc.y - mx) +
                         expf(acc.z - mx) + expf(acc.w - mx) : 0.f;
        #pragma unroll
        for (int o = 8; o > 0; o >>= 1) sm += __shfl_xor(sm, o, 16);
        if (act) {
            float l = mx + logf(sm);
            float4 o4 = {acc.x - l, acc.y - l, acc.z - l, acc.w - l};
            *(float4*)&out[(size_t)(node0 + ln) * NCLASS + l16 * 4] = o4;
        }
    }
}

extern "C" void kernel_launch(void* const* d_in, const int* in_sizes, int n_in,
                              void* d_out, int out_size, void* d_ws, size_t ws_size,
                              hipStream_t stream) {
    const float* features = (const float*)d_in[0];
    const int* edge_src   = (const int*)d_in[1];
    const int* edge_dst   = (const int*)d_in[2];
    const float* edge_w   = (const float*)d_in[3];
    const float* W1       = (const float*)d_in[4];
    const float* b1       = (const float*)d_in[5];
    const float* W2       = (const float*)d_in[6];
    const float* b2       = (const float*)d_in[7];
    float* out = (float*)d_out;

    // Workspace layout (bytes from base):
    //   h2:      fp32 [N,40]            @ 0          (16,000,000)
    //   h1b:     bf16 [N,128]           @ 51,200,000 (25,600,000)
    //   Wt:      bf16 [128,512]         @ 76,800,000 (131,072)
    //   histG:   int  [NBUCK*16]        @ 76,931,072 (100,032; 64B-padded)
    //   bofs:    int  [NBUCK+1]         @ 77,040,000 (6,256)
    //   bcursor: int  [NBUCK]           @ 77,050,000 (6,252)
    //   W2t:     bf16 [48,128]          @ 77,060,000 (12,288)
    //   sortedA: int2 [E]               @ 90,540,000 (12,800,000)
    char* base = (char*)d_ws;
    float*          h2       = (float*)base;
    unsigned short* h1b      = (unsigned short*)(base + 51200000);
    unsigned short* Wt       = (unsigned short*)(base + 76800000);
    int*            histG    = (int*)(base + 76931072);
    int*            bofs     = (int*)(base + 77040000);
    int*            bcursor  = (int*)(base + 77050000);
    unsigned short* W2t      = (unsigned short*)(base + 77060000);
    int2*           sortedA  = (int2*)(base + 90540000);

    hipMemsetAsync(histG, 0, NBUCK * 16 * sizeof(int), stream);

    // bucket hist + W1/W2 transpose fused (W2t: 24 tail blocks)
    bucket_hist_transpose_kernel<<<PNB + 256 + 24, 256, 0, stream>>>(
        edge_dst, histG, W1, Wt, W2, W2t, N_EDGES);
    bucket_scan_kernel<<<1, 1024, 0, stream>>>(histG, bofs, bcursor);

    // partition + gemm1 fused (independent work overlapped in one launch)
    partition_gemm1_kernel<<<FPNB + GEMM1_NB, 256, 0, stream>>>(
        edge_src, edge_dst, edge_w, bcursor, sortedA,
        features, Wt, h1b, N_EDGES, N_NODES);

    // Aggregate 1 + bias + relu + dense layer 2 (barrier-free + MFMA epilogue)
    agg1_gemm2_kernel<<<NBUCK, 256, 0, stream>>>(
        sortedA, bofs, h1b, b1, W2t, h2, N_NODES);

    // Aggregate 2 + bias + log_softmax (in-LDS counting sort)
    agg2_softmax_kernel<<<NBUCK, 256, 0, stream>>>(
        sortedA, bofs, h2, b2, out, N_NODES);
}